// Round 14
// baseline (4093.772 us; speedup 1.0000x reference)
//
#include <hip/hip_runtime.h>
#include <math.h>

#define DIM 768
#define DEPTH 12
#define HEADS 12
#define DIM_HEAD 64
#define DIM_MLP 3072
#define PATCH 16
#define NUM_PATCHES 256
#define SEQ 257
#define NUM_CLASSES 1000
#define BATCH 32
#define SCALE 0.125f
#define EPS 1e-5f
#define ROWS 8224         // BATCH*SEQ
#define PAD_ROWS 8320     // 65*128
#define PAD_A 8448

// V^T buffer geometry: [bh][64][VT_LD], bf16
#define VT_LD 296
#define VT_Z  (64 * VT_LD)

// per-layer transposed-weight element offsets
#define WL_QKV 0
#define WL_OW  (2304 * 768)
#define WL_W1  (WL_OW + 768 * 768)
#define WL_W2  (WL_W1 + 3072 * 768)
#define WL_TOT (WL_W2 + 768 * 3072)   // 14.16 MB

typedef short bf16x8 __attribute__((ext_vector_type(8)));
typedef float f32x4 __attribute__((ext_vector_type(4)));

__device__ inline unsigned short f2bf(float f) {
    union { float f; unsigned int u; } c; c.f = f;
    unsigned int u = c.u;
    return (unsigned short)((u + 0x7fffu + ((u >> 16) & 1u)) >> 16);
}

#define MFMA16(d, a, b) d = __builtin_amdgcn_mfma_f32_16x16x32_bf16(a, b, d, 0, 0, 0)
#define SBAR() asm volatile("s_barrier" ::: "memory")
#define LGKM0() asm volatile("s_waitcnt lgkmcnt(0)" ::: "memory")

// ---------------------------------------------------------------------------
// Patch embed (fp32)
// ---------------------------------------------------------------------------
__global__ void patch_embed_kernel(const float* __restrict__ x,
                                   const float* __restrict__ conv_w,
                                   const float* __restrict__ conv_b,
                                   const float* __restrict__ pos,
                                   const float* __restrict__ cls_tok,
                                   float* __restrict__ h) {
    int row = blockIdx.x;
    int b = row / SEQ;
    int r = row % SEQ;
    int t = threadIdx.x;
    float* out = h + (long)row * DIM;
    if (r == 0) {
        for (int d = t; d < DIM; d += 256)
            out[d] = cls_tok[d] + pos[d];
        return;
    }
    int p = r - 1;
    const float* xp = x + (long)b * 4096 + p * PATCH;
    float xv[PATCH];
#pragma unroll
    for (int k = 0; k < PATCH; ++k) xv[k] = xp[k];
    for (int d = t; d < DIM; d += 256) {
        float acc = conv_b[d];
#pragma unroll
        for (int k = 0; k < PATCH; ++k)
            acc += xv[k] * conv_w[k * DIM + d];
        out[d] = acc + pos[(long)r * DIM + d];
    }
}

// ---------------------------------------------------------------------------
// LayerNorm v2: one wave per row, float4, shfl_xor.
// ---------------------------------------------------------------------------
template <int OBF>
__global__ __launch_bounds__(256) void layernorm2_kernel(
    const float* __restrict__ in, long in_stride,
    const float* __restrict__ w, const float* __restrict__ bia,
    void* __restrict__ out) {
    long row = (long)blockIdx.x * 4 + (threadIdx.x >> 6);
    int lane = threadIdx.x & 63;
    const float4* src = (const float4*)(in + row * in_stride);
    float4 v[3];
#pragma unroll
    for (int k = 0; k < 3; ++k) v[k] = src[lane + 64 * k];
    float s = 0.f, q = 0.f;
#pragma unroll
    for (int k = 0; k < 3; ++k) {
        s += v[k].x + v[k].y + v[k].z + v[k].w;
        q += v[k].x * v[k].x + v[k].y * v[k].y + v[k].z * v[k].z + v[k].w * v[k].w;
    }
#pragma unroll
    for (int off = 1; off < 64; off <<= 1) {
        s += __shfl_xor(s, off);
        q += __shfl_xor(q, off);
    }
    float mu = s * (1.0f / DIM);
    float rstd = rsqrtf(q * (1.0f / DIM) - mu * mu + EPS);
    const float4* w4 = (const float4*)w;
    const float4* b4 = (const float4*)bia;
#pragma unroll
    for (int k = 0; k < 3; ++k) {
        float4 wv = w4[lane + 64 * k], bv = b4[lane + 64 * k];
        float o0 = (v[k].x - mu) * rstd * wv.x + bv.x;
        float o1 = (v[k].y - mu) * rstd * wv.y + bv.y;
        float o2 = (v[k].z - mu) * rstd * wv.z + bv.z;
        float o3 = (v[k].w - mu) * rstd * wv.w + bv.w;
        if (OBF) {
            ushort4 pv;
            pv.x = f2bf(o0); pv.y = f2bf(o1); pv.z = f2bf(o2); pv.w = f2bf(o3);
            ((ushort4*)((unsigned short*)out + row * DIM))[lane + 64 * k] = pv;
        } else {
            float4 ov = make_float4(o0, o1, o2, o3);
            ((float4*)((float*)out + row * DIM))[lane + 64 * k] = ov;
        }
    }
}

// ---------------------------------------------------------------------------
// Weight transpose v3: 64x64 tiles, float4 reads, bf16x8 writes, pad 69.
// ---------------------------------------------------------------------------
template <int LAYERS>
__global__ __launch_bounds__(256) void transpose_all_kernel(
    const float* __restrict__ qw, const float* __restrict__ ow,
    const float* __restrict__ w1, const float* __restrict__ w2,
    unsigned short* __restrict__ wOut) {
    __shared__ float tile[64][69];
    int t = blockIdx.x;
    int l = t / 1728; t -= l * 1728;
    const float* src; unsigned short* dst; int K, N, kt, nt;
    unsigned short* wL = wOut + (long)l * WL_TOT;
    if (t < 432)       {            src = qw + (long)l * 768 * 2304; dst = wL + WL_QKV; K = 768;  N = 2304; kt = t % 12; nt = t / 12; }
    else if (t < 576)  { t -= 432;  src = ow + (long)l * 768 * 768;  dst = wL + WL_OW;  K = 768;  N = 768;  kt = t % 12; nt = t / 12; }
    else if (t < 1152) { t -= 576;  src = w1 + (long)l * 768 * 3072; dst = wL + WL_W1;  K = 768;  N = 3072; kt = t % 12; nt = t / 12; }
    else               { t -= 1152; src = w2 + (long)l * 3072 * 768; dst = wL + WL_W2;  K = 3072; N = 768;  kt = t % 48; nt = t / 48; }
    int k0 = kt * 64, n0 = nt * 64;
    int tid = threadIdx.x;
    {
        int r0 = tid >> 4, c4 = (tid & 15) * 4;
#pragma unroll
        for (int p = 0; p < 4; ++p) {
            int r = r0 + p * 16;
            float4 v = *(const float4*)(src + (long)(k0 + r) * N + n0 + c4);
            tile[r][c4 + 0] = v.x; tile[r][c4 + 1] = v.y;
            tile[r][c4 + 2] = v.z; tile[r][c4 + 3] = v.w;
        }
    }
    __syncthreads();
    {
        int nr0 = tid >> 3, kc8 = (tid & 7) * 8;
#pragma unroll
        for (int p = 0; p < 2; ++p) {
            int nr = nr0 + p * 32;
            short vv[8];
#pragma unroll
            for (int e = 0; e < 8; ++e)
                vv[e] = (short)f2bf(tile[kc8 + e][nr]);
            *(bf16x8*)(dst + (long)(n0 + nr) * K + k0 + kc8) = *(bf16x8*)vv;
        }
    }
}

// ---------------------------------------------------------------------------
// V repack: vt[bh][d][j] = V[b,j,h,d] (bf16), j>=257 zeroed.
// ---------------------------------------------------------------------------
__global__ __launch_bounds__(256) void v_repack2_kernel(
    const unsigned short* __restrict__ qkv, unsigned short* __restrict__ vt) {
    __shared__ unsigned short lds[257 * 69 + 3];
    int z = blockIdx.x;
    int b = z / HEADS, hh = z % HEADS;
    const unsigned short* vbase = qkv + (long)b * SEQ * 2304 + 1536 + hh * 64;
    int tid = threadIdx.x;
    for (int u = tid; u < 257 * 8; u += 256) {
        int j = u >> 3, dc = u & 7;
        bf16x8 v8 = *(const bf16x8*)(vbase + (long)j * 2304 + dc * 8);
#pragma unroll
        for (int e = 0; e < 8; ++e)
            lds[j * 69 + dc * 8 + e] = (unsigned short)v8[e];
    }
    __syncthreads();
    unsigned short* out = vt + (long)z * VT_Z;
    for (int w = tid; w < 64 * 37; w += 256) {
        int d = w / 37, jc = w % 37;
        short vv[8];
#pragma unroll
        for (int e = 0; e < 8; ++e) {
            int j = jc * 8 + e;
            vv[e] = (j < SEQ) ? (short)lds[j * 69 + d] : (short)0;
        }
        *(bf16x8*)(out + d * VT_LD + jc * 8) = *(bf16x8*)vv;
    }
}

// ---------------------------------------------------------------------------
// Fused attention v3 (R10 proven): 512 threads, 128 Q-rows/block.
// ---------------------------------------------------------------------------
__global__ __launch_bounds__(512) void attn2_kernel(const unsigned short* __restrict__ qkv,
                                                    const unsigned short* __restrict__ vt,
                                                    unsigned short* __restrict__ o) {
    __shared__ unsigned short sh[75264];
    const int tid = threadIdx.x;
    const int lane = tid & 63;
    const int w = tid >> 6;

    const int nwg = gridDim.x;
    const int orig = blockIdx.x;
    const int q = nwg >> 3, r = nwg & 7;
    const int xcd = orig & 7, idx = orig >> 3;
    const int wg = (xcd < r ? xcd * (q + 1) : r * (q + 1) + (xcd - r) * q) + idx;
    const int bh = wg / 3, qc = wg % 3;
    const int b = bh / HEADS, hh = bh % HEADS;
    const unsigned short* qbase = qkv + (long)b * SEQ * 2304 + hh * 64;
    const unsigned short* kbase = qbase + 768;

#pragma unroll
    for (int u = 0; u < 5; ++u) {
        int c = tid + u * 512;
        if (c < 2304) {
            int j = c >> 3, cb = c & 7;
            int gj = j > 256 ? 256 : j;
            const unsigned short* g = kbase + (long)gj * 2304 + ((cb ^ (j & 7)) << 3);
            __builtin_amdgcn_global_load_lds(
                (const __attribute__((address_space(1))) void*)g,
                (__attribute__((address_space(3))) void*)&sh[j * 64 + cb * 8], 16, 0, 0);
        }
    }
#pragma unroll
    for (int u = 0; u < 5; ++u) {
        int c = tid + u * 512;
        if (c < 2368) {
            const unsigned short* g = vt + (long)bh * VT_Z + c * 8;
            __builtin_amdgcn_global_load_lds(
                (const __attribute__((address_space(1))) void*)g,
                (__attribute__((address_space(3))) void*)&sh[18432 + c * 8], 16, 0, 0);
        }
    }
    __syncthreads();

    const int arow = qc * 128 + w * 16 + (lane & 15);
    const int garow = arow > 256 ? 256 : arow;
    f32x4 s[18] = {};
#pragma unroll
    for (int ks = 0; ks < 2; ++ks) {
        bf16x8 aq = *(const bf16x8*)(qbase + (long)garow * 2304 + ks * 32 + (lane >> 4) * 8);
        int cb = ks * 4 + (lane >> 4);
#pragma unroll
        for (int nf = 0; nf < 18; ++nf) {
            int brow = nf * 16 + (lane & 15);
            bf16x8 bk = *(const bf16x8*)&sh[brow * 64 + ((cb ^ (brow & 7)) << 3)];
            MFMA16(s[nf], aq, bk);
        }
    }

    float inv[4];
#pragma unroll
    for (int j = 0; j < 4; ++j) {
        float m_ = -3.0e38f;
#pragma unroll
        for (int nf = 0; nf < 18; ++nf) {
            int col = nf * 16 + (lane & 15);
            float xv = (col < SEQ) ? s[nf][j] * SCALE : -3.0e38f;
            s[nf][j] = xv;
            m_ = fmaxf(m_, xv);
        }
#pragma unroll
        for (int off = 1; off < 16; off <<= 1) m_ = fmaxf(m_, __shfl_xor(m_, off));
        float sm = 0.f;
#pragma unroll
        for (int nf = 0; nf < 18; ++nf) {
            float e = __expf(s[nf][j] - m_);
            s[nf][j] = e;
            sm += e;
        }
#pragma unroll
        for (int off = 1; off < 16; off <<= 1) sm += __shfl_xor(sm, off);
        inv[j] = 1.0f / sm;
    }
#pragma unroll
    for (int nf = 0; nf < 18; ++nf) {
        int col = nf * 16 + (lane & 15);
#pragma unroll
        for (int j = 0; j < 4; ++j) {
            int row = w * 16 + (lane >> 4) * 4 + j;
            sh[37376 + row * 296 + col] = f2bf(s[nf][j] * inv[j]);
        }
    }
    __syncthreads();

    f32x4 oa[4] = {};
    const int prow = w * 16 + (lane & 15);
#pragma unroll
    for (int ks = 0; ks < 9; ++ks) {
        bf16x8 ap = *(const bf16x8*)&sh[37376 + prow * 296 + ks * 32 + (lane >> 4) * 8];
#pragma unroll
        for (int n = 0; n < 4; ++n) {
            int drow = n * 16 + (lane & 15);
            bf16x8 bv = *(const bf16x8*)&sh[18432 + drow * VT_LD + ks * 32 + (lane >> 4) * 8];
            MFMA16(oa[n], ap, bv);
        }
    }
#pragma unroll
    for (int n = 0; n < 4; ++n) {
        int col = hh * 64 + n * 16 + (lane & 15);
#pragma unroll
        for (int j = 0; j < 4; ++j) {
            int gr = qc * 128 + w * 16 + (lane >> 4) * 4 + j;
            if (gr < SEQ)
                o[((long)(b * SEQ + gr)) * DIM + col] = f2bf(oa[n][j]);
        }
    }
}

// ---------------------------------------------------------------------------
// 128x128 / BK=64 / dbuf 64KB / 2 blocks/CU bf16 MFMA GEMM (R6 proven).
// SPLIT=1: blockIdx.y = K-half; both halves atomicAdd fp32 into C (which
// already holds the residual); half 0 adds bias.  Removes the resid read.
// ---------------------------------------------------------------------------
template <int NK, int ACT, int OBF, int SPLIT>
__global__ __launch_bounds__(256, 2) void gemmd_kernel(
    const unsigned short* __restrict__ A,
    const unsigned short* __restrict__ Bt,
    const float* __restrict__ bias,
    const float* __restrict__ resid,
    void* __restrict__ C,
    int M, int GY, int lda, int ldb, int ldc) {
    __shared__ unsigned short sh[32768];
    const int tid = threadIdx.x;
    const int lane = tid & 63;
    const int w = tid >> 6;
    const int wr = w >> 1, wc = w & 1;

    const int nwg = gridDim.x;
    const int orig = blockIdx.x;
    const int q = nwg >> 3, r = nwg & 7;
    const int xcd = orig & 7, idx = orig >> 3;
    const int wg = (xcd < r ? xcd * (q + 1) : r * (q + 1) + (xcd - r) * q) + idx;
    const int bm = (wg / GY) * 128;
    const int bn = (wg % GY) * 128;
    const int half = SPLIT ? blockIdx.y : 0;

    const unsigned short* Ag = A + (long)bm * lda + (SPLIT ? half * NK * 64 : 0);
    const unsigned short* Bg = Bt + (long)bn * ldb + (SPLIT ? half * NK * 64 : 0);

    auto stage = [&](int kt) {
        unsigned short* La = &sh[(kt & 1) * 16384];
        unsigned short* Lb = La + 8192;
#pragma unroll
        for (int u = 0; u < 4; ++u) {
            int c = tid + u * 256;
            int lr = c >> 3, cb = c & 7;
            int sw = (cb ^ (lr & 7)) << 3;
            const unsigned short* ga = Ag + (long)lr * lda + kt * 64 + sw;
            __builtin_amdgcn_global_load_lds(
                (const __attribute__((address_space(1))) void*)ga,
                (__attribute__((address_space(3))) void*)&La[lr * 64 + (cb << 3)], 16, 0, 0);
            const unsigned short* gb = Bg + (long)lr * ldb + kt * 64 + sw;
            __builtin_amdgcn_global_load_lds(
                (const __attribute__((address_space(1))) void*)gb,
                (__attribute__((address_space(3))) void*)&Lb[lr * 64 + (cb << 3)], 16, 0, 0);
        }
    };
    auto ldA = [&](int p, int m, int ks) {
        int row = wr * 64 + m * 16 + (lane & 15);
        int cb = ks * 4 + (lane >> 4);
        return *(const bf16x8*)&sh[p * 16384 + row * 64 + ((cb ^ (row & 7)) << 3)];
    };
    auto ldB = [&](int p, int n, int ks) {
        int row = wc * 64 + n * 16 + (lane & 15);
        int cb = ks * 4 + (lane >> 4);
        return *(const bf16x8*)&sh[p * 16384 + 8192 + row * 64 + ((cb ^ (row & 7)) << 3)];
    };

    f32x4 acc[4][4] = {};

    stage(0); stage(1);
    asm volatile("s_waitcnt vmcnt(8)" ::: "memory");
    SBAR();

    for (int kt = 0; kt < NK; ++kt) {
        const int p = kt & 1;
        bf16x8 a[4][2], b[4][2];
#pragma unroll
        for (int m = 0; m < 4; ++m) { a[m][0] = ldA(p, m, 0); a[m][1] = ldA(p, m, 1); }
#pragma unroll
        for (int n = 0; n < 4; ++n) { b[n][0] = ldB(p, n, 0); b[n][1] = ldB(p, n, 1); }
        SBAR();
        if (kt + 2 < NK) stage(kt + 2);
        LGKM0();
        __builtin_amdgcn_s_setprio(1);
#pragma unroll
        for (int m = 0; m < 4; ++m)
#pragma unroll
            for (int n = 0; n < 4; ++n) {
                MFMA16(acc[m][n], a[m][0], b[n][0]);
                MFMA16(acc[m][n], a[m][1], b[n][1]);
            }
        __builtin_amdgcn_s_setprio(0);
        if (kt + 2 < NK) {
            asm volatile("s_waitcnt vmcnt(8)" ::: "memory");
        } else if (kt + 1 < NK) {
            asm volatile("s_waitcnt vmcnt(0)" ::: "memory");
        }
        SBAR();
    }

#pragma unroll
    for (int mi = 0; mi < 4; ++mi) {
        int gr0 = bm + wr * 64 + mi * 16 + (lane >> 4) * 4;
#pragma unroll
        for (int ni = 0; ni < 4; ++ni) {
            int gc = bn + wc * 64 + ni * 16 + (lane & 15);
            float bv = (bias && (!SPLIT || half == 0)) ? bias[gc] : 0.f;
#pragma unroll
            for (int j = 0; j < 4; ++j) {
                int gr = gr0 + j;
                if (gr >= M) continue;
                float v = acc[mi][ni][j] + bv;
                if (ACT) v = 0.5f * v * (1.0f + erff(v * 0.70710678118654752f));
                long ci = (long)gr * ldc + gc;
                if (SPLIT) {
                    atomicAdd(&((float*)C)[ci], v);
                } else if (OBF) {
                    ((unsigned short*)C)[ci] = f2bf(v);
                } else {
                    if (resid) v += resid[ci];
                    ((float*)C)[ci] = v;
                }
            }
        }
    }
}

// ---------------------------------------------------------------------------
// 128x128 / BK=32 / dbuf 32KB / 4 blocks/CU (R10 proven) — qkv + mlp1.
// ---------------------------------------------------------------------------
template <int NK, int ACT, int OBF>
__global__ __launch_bounds__(256, 4) void gemmd32_kernel(
    const unsigned short* __restrict__ A,
    const unsigned short* __restrict__ Bt,
    const float* __restrict__ bias,
    const float* __restrict__ resid,
    void* __restrict__ C,
    int M, int GY, int lda, int ldb, int ldc) {
    __shared__ unsigned short sh[16384];
    const int tid = threadIdx.x;
    const int lane = tid & 63;
    const int w = tid >> 6;
    const int wr = w >> 1, wc = w & 1;

    const int nwg = gridDim.x;
    const int orig = blockIdx.x;
    const int q = nwg >> 3, r = nwg & 7;
    const int xcd = orig & 7, idx = orig >> 3;
    const int wg = (xcd < r ? xcd * (q + 1) : r * (q + 1) + (xcd - r) * q) + idx;
    const int bm = (wg / GY) * 128;
    const int bn = (wg % GY) * 128;

    const unsigned short* Ag = A + (long)bm * lda;
    const unsigned short* Bg = Bt + (long)bn * ldb;

    auto stage = [&](int kt) {
        unsigned short* La = &sh[(kt & 1) * 8192];
        unsigned short* Lb = La + 4096;
#pragma unroll
        for (int u = 0; u < 2; ++u) {
            int c = tid + u * 256;
            int lr = c >> 2, cb = c & 3;
            int sw = (cb ^ (lr & 3)) << 3;
            const unsigned short* ga = Ag + (long)lr * lda + kt * 32 + sw;
            __builtin_amdgcn_global_load_lds(
                (const __attribute__((address_space(1))) void*)ga,
                (__attribute__((address_space(3))) void*)&La[lr * 32 + (cb << 3)], 16, 0, 0);
            const unsigned short* gb = Bg + (long)lr * ldb + kt * 32 + sw;
            __builtin_amdgcn_global_load_lds(
                (const __attribute__((address_space(1))) void*)gb,
                (__attribute__((address_space(3))) void*)&Lb[lr * 32 + (cb << 3)], 16, 0, 0);
        }
    };
    auto ldA = [&](int p, int m) {
        int row = wr * 64 + m * 16 + (lane & 15);
        int cb = lane >> 4;
        return *(const bf16x8*)&sh[p * 8192 + row * 32 + ((cb ^ (row & 3)) << 3)];
    };
    auto ldB = [&](int p, int n) {
        int row = wc * 64 + n * 16 + (lane & 15);
        int cb = lane >> 4;
        return *(const bf16x8*)&sh[p * 8192 + 4096 + row * 32 + ((cb ^ (row & 3)) << 3)];
    };

    f32x4 acc[4][4] = {};

    stage(0); stage(1);
    asm volatile("s_waitcnt vmcnt(4)" ::: "memory");
    SBAR();

    for (int kt = 0; kt < NK; ++kt) {
        const int p = kt & 1;
        bf16x8 a[4], b[4];
#pragma unroll
        for (int m = 0; m < 4; ++m) a[m] = ldA(p, m);
#pragma unroll
        for (int n = 0; n < 4; ++n) b[n] = ldB(p, n);
        SBAR();
        if (kt + 2 < NK) stage(kt + 2);
        LGKM0();
        __builtin_amdgcn_s_setprio(1);
#pragma unroll
        for (int m = 0; m < 4; ++m)
#pragma unroll
            for (int n = 0; n < 4; ++n)
                MFMA16(acc[m][n], a[m], b[n]);
        __builtin_amdgcn_s_setprio(0);
        if (kt + 2 < NK) {
            asm volatile("s_waitcnt vmcnt(4)" ::: "memory");
        } else if (kt + 1 < NK) {
            asm volatile("s_waitcnt vmcnt(0)" ::: "memory");
        }
        SBAR();
    }

#pragma unroll
    for (int mi = 0; mi < 4; ++mi) {
        int gr0 = bm + wr * 64 + mi * 16 + (lane >> 4) * 4;
#pragma unroll
        for (int ni = 0; ni < 4; ++ni) {
            int gc = bn + wc * 64 + ni * 16 + (lane & 15);
            float bv = bias ? bias[gc] : 0.f;
#pragma unroll
            for (int j = 0; j < 4; ++j) {
                int gr = gr0 + j;
                if (gr >= M) continue;
                float v = acc[mi][ni][j] + bv;
                if (ACT) v = 0.5f * v * (1.0f + erff(v * 0.70710678118654752f));
                long ci = (long)gr * ldc + gc;
                if (OBF) {
                    ((unsigned short*)C)[ci] = f2bf(v);
                } else {
                    if (resid) v += resid[ci];
                    ((float*)C)[ci] = v;
                }
            }
        }
    }
}

// ---------------------------------------------------------------------------
// fp32 GEMM for the tiny classifier head
// ---------------------------------------------------------------------------
__global__ void gemm_f32_kernel(const float* __restrict__ A,
                                const float* __restrict__ W,
                                const float* __restrict__ bias,
                                float* __restrict__ C,
                                int M, int N, int K) {
    __shared__ float As[16][65];
    __shared__ float Bs[16][65];
    int bm = blockIdx.x * 64, bn = blockIdx.y * 64;
    int t = threadIdx.x;
    int tx = t & 15, ty = t >> 4;
    float acc[4][4] = {};
    for (int k0 = 0; k0 < K; k0 += 16) {
        {
            int ar = bm + (t >> 2);
            int ac = k0 + (t & 3) * 4;
            float4 av = make_float4(0.f, 0.f, 0.f, 0.f);
            if (ar < M) av = *(const float4*)(A + (long)ar * K + ac);
            int kk = (t & 3) * 4, rr = t >> 2;
            As[kk + 0][rr] = av.x; As[kk + 1][rr] = av.y;
            As[kk + 2][rr] = av.z; As[kk + 3][rr] = av.w;
        }
        {
            int wr2 = k0 + (t >> 4);
            int wc2 = bn + (t & 15) * 4;
            float4 wv;
            wv.x = (wc2 + 0 < N) ? W[(long)wr2 * N + wc2 + 0] : 0.f;
            wv.y = (wc2 + 1 < N) ? W[(long)wr2 * N + wc2 + 1] : 0.f;
            wv.z = (wc2 + 2 < N) ? W[(long)wr2 * N + wc2 + 2] : 0.f;
            wv.w = (wc2 + 3 < N) ? W[(long)wr2 * N + wc2 + 3] : 0.f;
            int kr = t >> 4, nc = (t & 15) * 4;
            Bs[kr][nc + 0] = wv.x; Bs[kr][nc + 1] = wv.y;
            Bs[kr][nc + 2] = wv.z; Bs[kr][nc + 3] = wv.w;
        }
        __syncthreads();
#pragma unroll
        for (int kk = 0; kk < 16; ++kk) {
            float a0 = As[kk][ty * 4 + 0], a1 = As[kk][ty * 4 + 1];
            float a2 = As[kk][ty * 4 + 2], a3 = As[kk][ty * 4 + 3];
            float b0 = Bs[kk][tx], b1 = Bs[kk][tx + 16];
            float b2 = Bs[kk][tx + 32], b3 = Bs[kk][tx + 48];
            acc[0][0] += a0 * b0; acc[0][1] += a0 * b1; acc[0][2] += a0 * b2; acc[0][3] += a0 * b3;
            acc[1][0] += a1 * b0; acc[1][1] += a1 * b1; acc[1][2] += a1 * b2; acc[1][3] += a1 * b3;
            acc[2][0] += a2 * b0; acc[2][1] += a2 * b1; acc[2][2] += a2 * b2; acc[2][3] += a2 * b3;
            acc[3][0] += a3 * b0; acc[3][1] += a3 * b1; acc[3][2] += a3 * b2; acc[3][3] += a3 * b3;
        }
        __syncthreads();
    }
#pragma unroll
    for (int i = 0; i < 4; ++i) {
        int r = bm + ty * 4 + i;
        if (r >= M) continue;
#pragma unroll
        for (int j = 0; j < 4; ++j) {
            int c = bn + tx + 16 * j;
            if (c >= N) continue;
            C[(long)r * N + c] = acc[i][j] + (bias ? bias[c] : 0.f);
        }
    }
}

// ---------------------------------------------------------------------------
// Orchestration
// ---------------------------------------------------------------------------
extern "C" void kernel_launch(void* const* d_in, const int* in_sizes, int n_in,
                              void* d_out, int out_size, void* d_ws, size_t ws_size,
                              hipStream_t stream) {
    const float* x        = (const float*)d_in[0];
    const float* conv_w   = (const float*)d_in[1];
    const float* conv_b   = (const float*)d_in[2];
    const float* pos      = (const float*)d_in[3];
    const float* cls_tok  = (const float*)d_in[4];
    const float* ln1_w    = (const float*)d_in[5];
    const float* ln1_b    = (const float*)d_in[6];
    const float* qkv_w    = (const float*)d_in[7];
    const float* out_w    = (const float*)d_in[8];
    const float* out_b    = (const float*)d_in[9];
    const float* ln2_w    = (const float*)d_in[10];
    const float* ln2_b    = (const float*)d_in[11];
    const float* mlp_w1   = (const float*)d_in[12];
    const float* mlp_b1   = (const float*)d_in[13];
    const float* mlp_w2   = (const float*)d_in[14];
    const float* mlp_b2   = (const float*)d_in[15];
    const float* cls_ln_w = (const float*)d_in[16];
    const float* cls_ln_b = (const float*)d_in[17];
    const float* head_w   = (const float*)d_in[18];
    const float* head_b   = (const float*)d_in[19];
    float* out = (float*)d_out;

    char* cur = (char*)d_ws;
    auto alloc = [&](size_t bytes) {
        void* p = cur; cur += (bytes + 255) & ~(size_t)255; return p;
    };
    float*          h      = (float*)alloc((size_t)PAD_ROWS * DIM * 4);
    unsigned short* z_bf   = (unsigned short*)alloc((size_t)PAD_A * DIM * 2);
    unsigned short* qkv_bf = (unsigned short*)alloc((size_t)ROWS * 3 * DIM * 2);
    unsigned short* o_bf   = (unsigned short*)alloc((size_t)PAD_ROWS * DIM * 2);
    unsigned short* m1     = (unsigned short*)alloc((size_t)PAD_ROWS * DIM_MLP * 2);
    unsigned short* vt     = (unsigned short*)alloc((size_t)BATCH * HEADS * VT_Z * 2);
    float*          clsz   = (float*)alloc((size_t)BATCH * DIM * 4);
    size_t used = (size_t)(cur - (char*)d_ws);
    bool all_layers = (ws_size - used) >= (size_t)12 * WL_TOT * 2 + 256;
    unsigned short* wAll = (unsigned short*)alloc((all_layers ? (size_t)12 : (size_t)1) * WL_TOT * 2);

    patch_embed_kernel<<<ROWS, 256, 0, stream>>>(x, conv_w, conv_b, pos, cls_tok, h);

    if (all_layers)
        transpose_all_kernel<12><<<12 * 1728, 256, 0, stream>>>(
            qkv_w, out_w, mlp_w1, mlp_w2, wAll);

    for (int l = 0; l < DEPTH; ++l) {
        unsigned short* wL = wAll + (all_layers ? (long)l * WL_TOT : 0);
        if (!all_layers)
            transpose_all_kernel<1><<<1728, 256, 0, stream>>>(
                qkv_w + (long)l * DIM * 3 * DIM, out_w + (long)l * DIM * DIM,
                mlp_w1 + (long)l * DIM * DIM_MLP, mlp_w2 + (long)l * DIM_MLP * DIM, wL);
        unsigned short* qkvwT = wL + WL_QKV;
        unsigned short* owT   = wL + WL_OW;
        unsigned short* w1T   = wL + WL_W1;
        unsigned short* w2T   = wL + WL_W2;

        layernorm2_kernel<1><<<ROWS / 4, 256, 0, stream>>>(
            h, DIM, ln1_w + (long)l * DIM, ln1_b + (long)l * DIM, z_bf);

        // qkv = z @ qkv_w   [8224 x 2304], K=768  (BK=32, 4 blk/CU)
        gemmd32_kernel<24, 0, 1><<<65 * 18, 256, 0, stream>>>(
            z_bf, qkvwT, nullptr, nullptr, qkv_bf, ROWS, 18, DIM, DIM, 3 * DIM);

        // V^T repack then fused attention
        v_repack2_kernel<<<BATCH * HEADS, 256, 0, stream>>>(qkv_bf, vt);
        attn2_kernel<<<384 * 3, 512, 0, stream>>>(qkv_bf, vt, o_bf);

        // h = o @ out_w + out_b + h   (fp32, in-place residual), K=768 (R11 proven)
        gemmd_kernel<12, 0, 0, 0><<<65 * 6, 256, 0, stream>>>(
            o_bf, owT, out_b + (long)l * DIM, h, h, ROWS, 6, DIM, DIM, DIM);

        layernorm2_kernel<1><<<ROWS / 4, 256, 0, stream>>>(
            h, DIM, ln2_w + (long)l * DIM, ln2_b + (long)l * DIM, z_bf);

        // m1 = gelu(z @ w1 + b1)   [8224 x 3072], K=768  (BK=32, 4 blk/CU)
        gemmd32_kernel<24, 1, 1><<<65 * 24, 256, 0, stream>>>(
            z_bf, w1T, mlp_b1 + (long)l * DIM_MLP, nullptr, m1, ROWS, 24, DIM, DIM, DIM_MLP);

        // h += m1 @ w2 + b2   split-K=2, atomic fp32 epilogue (h holds resid)
        gemmd_kernel<24, 0, 0, 1><<<dim3(65 * 6, 2), 256, 0, stream>>>(
            m1, w2T, mlp_b2 + (long)l * DIM, nullptr, h, ROWS, 6, DIM_MLP, DIM_MLP, DIM);
    }

    layernorm2_kernel<0><<<BATCH / 4, 256, 0, stream>>>(
        h, (long)SEQ * DIM, cls_ln_w, cls_ln_b, clsz);
    gemm_f32_kernel<<<dim3(1, 16), 256, 0, stream>>>(
        clsz, head_w, head_b, out, BATCH, NUM_CLASSES, DIM);
}

// Round 15
// 4093.330 us; speedup vs baseline: 1.0001x; 1.0001x over previous
//
#include <hip/hip_runtime.h>
#include <math.h>

#define DIM 768
#define DEPTH 12
#define HEADS 12
#define DIM_HEAD 64
#define DIM_MLP 3072
#define PATCH 16
#define NUM_PATCHES 256
#define SEQ 257
#define NUM_CLASSES 1000
#define BATCH 32
#define SCALE 0.125f
#define EPS 1e-5f
#define ROWS 8224         // BATCH*SEQ
#define PAD_ROWS 8320     // 65*128
#define PAD_A 8448

// V^T buffer geometry: [bh][64][VT_LD], bf16
#define VT_LD 296
#define VT_Z  (64 * VT_LD)

// per-layer transposed-weight element offsets
#define WL_QKV 0
#define WL_OW  (2304 * 768)
#define WL_W1  (WL_OW + 768 * 768)
#define WL_W2  (WL_W1 + 3072 * 768)
#define WL_TOT (WL_W2 + 768 * 3072)   // 14.16 MB

typedef short bf16x8 __attribute__((ext_vector_type(8)));
typedef float f32x4 __attribute__((ext_vector_type(4)));

__device__ inline unsigned short f2bf(float f) {
    union { float f; unsigned int u; } c; c.f = f;
    unsigned int u = c.u;
    return (unsigned short)((u + 0x7fffu + ((u >> 16) & 1u)) >> 16);
}

#define MFMA16(d, a, b) d = __builtin_amdgcn_mfma_f32_16x16x32_bf16(a, b, d, 0, 0, 0)
#define SBAR() asm volatile("s_barrier" ::: "memory")
#define LGKM0() asm volatile("s_waitcnt lgkmcnt(0)" ::: "memory")

// ---------------------------------------------------------------------------
// Patch embed (fp32)
// ---------------------------------------------------------------------------
__global__ void patch_embed_kernel(const float* __restrict__ x,
                                   const float* __restrict__ conv_w,
                                   const float* __restrict__ conv_b,
                                   const float* __restrict__ pos,
                                   const float* __restrict__ cls_tok,
                                   float* __restrict__ h) {
    int row = blockIdx.x;
    int b = row / SEQ;
    int r = row % SEQ;
    int t = threadIdx.x;
    float* out = h + (long)row * DIM;
    if (r == 0) {
        for (int d = t; d < DIM; d += 256)
            out[d] = cls_tok[d] + pos[d];
        return;
    }
    int p = r - 1;
    const float* xp = x + (long)b * 4096 + p * PATCH;
    float xv[PATCH];
#pragma unroll
    for (int k = 0; k < PATCH; ++k) xv[k] = xp[k];
    for (int d = t; d < DIM; d += 256) {
        float acc = conv_b[d];
#pragma unroll
        for (int k = 0; k < PATCH; ++k)
            acc += xv[k] * conv_w[k * DIM + d];
        out[d] = acc + pos[(long)r * DIM + d];
    }
}

// ---------------------------------------------------------------------------
// LayerNorm v2: one wave per row, float4, shfl_xor.
// ---------------------------------------------------------------------------
template <int OBF>
__global__ __launch_bounds__(256) void layernorm2_kernel(
    const float* __restrict__ in, long in_stride,
    const float* __restrict__ w, const float* __restrict__ bia,
    void* __restrict__ out) {
    long row = (long)blockIdx.x * 4 + (threadIdx.x >> 6);
    int lane = threadIdx.x & 63;
    const float4* src = (const float4*)(in + row * in_stride);
    float4 v[3];
#pragma unroll
    for (int k = 0; k < 3; ++k) v[k] = src[lane + 64 * k];
    float s = 0.f, q = 0.f;
#pragma unroll
    for (int k = 0; k < 3; ++k) {
        s += v[k].x + v[k].y + v[k].z + v[k].w;
        q += v[k].x * v[k].x + v[k].y * v[k].y + v[k].z * v[k].z + v[k].w * v[k].w;
    }
#pragma unroll
    for (int off = 1; off < 64; off <<= 1) {
        s += __shfl_xor(s, off);
        q += __shfl_xor(q, off);
    }
    float mu = s * (1.0f / DIM);
    float rstd = rsqrtf(q * (1.0f / DIM) - mu * mu + EPS);
    const float4* w4 = (const float4*)w;
    const float4* b4 = (const float4*)bia;
#pragma unroll
    for (int k = 0; k < 3; ++k) {
        float4 wv = w4[lane + 64 * k], bv = b4[lane + 64 * k];
        float o0 = (v[k].x - mu) * rstd * wv.x + bv.x;
        float o1 = (v[k].y - mu) * rstd * wv.y + bv.y;
        float o2 = (v[k].z - mu) * rstd * wv.z + bv.z;
        float o3 = (v[k].w - mu) * rstd * wv.w + bv.w;
        if (OBF) {
            ushort4 pv;
            pv.x = f2bf(o0); pv.y = f2bf(o1); pv.z = f2bf(o2); pv.w = f2bf(o3);
            ((ushort4*)((unsigned short*)out + row * DIM))[lane + 64 * k] = pv;
        } else {
            float4 ov = make_float4(o0, o1, o2, o3);
            ((float4*)((float*)out + row * DIM))[lane + 64 * k] = ov;
        }
    }
}

// ---------------------------------------------------------------------------
// Weight transpose v3: 64x64 tiles, float4 reads, bf16x8 writes, pad 69.
// ---------------------------------------------------------------------------
template <int LAYERS>
__global__ __launch_bounds__(256) void transpose_all_kernel(
    const float* __restrict__ qw, const float* __restrict__ ow,
    const float* __restrict__ w1, const float* __restrict__ w2,
    unsigned short* __restrict__ wOut) {
    __shared__ float tile[64][69];
    int t = blockIdx.x;
    int l = t / 1728; t -= l * 1728;
    const float* src; unsigned short* dst; int K, N, kt, nt;
    unsigned short* wL = wOut + (long)l * WL_TOT;
    if (t < 432)       {            src = qw + (long)l * 768 * 2304; dst = wL + WL_QKV; K = 768;  N = 2304; kt = t % 12; nt = t / 12; }
    else if (t < 576)  { t -= 432;  src = ow + (long)l * 768 * 768;  dst = wL + WL_OW;  K = 768;  N = 768;  kt = t % 12; nt = t / 12; }
    else if (t < 1152) { t -= 576;  src = w1 + (long)l * 768 * 3072; dst = wL + WL_W1;  K = 768;  N = 3072; kt = t % 12; nt = t / 12; }
    else               { t -= 1152; src = w2 + (long)l * 3072 * 768; dst = wL + WL_W2;  K = 3072; N = 768;  kt = t % 48; nt = t / 48; }
    int k0 = kt * 64, n0 = nt * 64;
    int tid = threadIdx.x;
    {
        int r0 = tid >> 4, c4 = (tid & 15) * 4;
#pragma unroll
        for (int p = 0; p < 4; ++p) {
            int r = r0 + p * 16;
            float4 v = *(const float4*)(src + (long)(k0 + r) * N + n0 + c4);
            tile[r][c4 + 0] = v.x; tile[r][c4 + 1] = v.y;
            tile[r][c4 + 2] = v.z; tile[r][c4 + 3] = v.w;
        }
    }
    __syncthreads();
    {
        int nr0 = tid >> 3, kc8 = (tid & 7) * 8;
#pragma unroll
        for (int p = 0; p < 2; ++p) {
            int nr = nr0 + p * 32;
            short vv[8];
#pragma unroll
            for (int e = 0; e < 8; ++e)
                vv[e] = (short)f2bf(tile[kc8 + e][nr]);
            *(bf16x8*)(dst + (long)(n0 + nr) * K + k0 + kc8) = *(bf16x8*)vv;
        }
    }
}

// ---------------------------------------------------------------------------
// V repack: vt[bh][d][j] = V[b,j,h,d] (bf16), j>=257 zeroed.
// ---------------------------------------------------------------------------
__global__ __launch_bounds__(256) void v_repack2_kernel(
    const unsigned short* __restrict__ qkv, unsigned short* __restrict__ vt) {
    __shared__ unsigned short lds[257 * 69 + 3];
    int z = blockIdx.x;
    int b = z / HEADS, hh = z % HEADS;
    const unsigned short* vbase = qkv + (long)b * SEQ * 2304 + 1536 + hh * 64;
    int tid = threadIdx.x;
    for (int u = tid; u < 257 * 8; u += 256) {
        int j = u >> 3, dc = u & 7;
        bf16x8 v8 = *(const bf16x8*)(vbase + (long)j * 2304 + dc * 8);
#pragma unroll
        for (int e = 0; e < 8; ++e)
            lds[j * 69 + dc * 8 + e] = (unsigned short)v8[e];
    }
    __syncthreads();
    unsigned short* out = vt + (long)z * VT_Z;
    for (int w = tid; w < 64 * 37; w += 256) {
        int d = w / 37, jc = w % 37;
        short vv[8];
#pragma unroll
        for (int e = 0; e < 8; ++e) {
            int j = jc * 8 + e;
            vv[e] = (j < SEQ) ? (short)lds[j * 69 + d] : (short)0;
        }
        *(bf16x8*)(out + d * VT_LD + jc * 8) = *(bf16x8*)vv;
    }
}

// ---------------------------------------------------------------------------
// Fused attention v3 (R10 proven): 512 threads, 128 Q-rows/block.
// ---------------------------------------------------------------------------
__global__ __launch_bounds__(512) void attn2_kernel(const unsigned short* __restrict__ qkv,
                                                    const unsigned short* __restrict__ vt,
                                                    unsigned short* __restrict__ o) {
    __shared__ unsigned short sh[75264];
    const int tid = threadIdx.x;
    const int lane = tid & 63;
    const int w = tid >> 6;

    const int nwg = gridDim.x;
    const int orig = blockIdx.x;
    const int q = nwg >> 3, r = nwg & 7;
    const int xcd = orig & 7, idx = orig >> 3;
    const int wg = (xcd < r ? xcd * (q + 1) : r * (q + 1) + (xcd - r) * q) + idx;
    const int bh = wg / 3, qc = wg % 3;
    const int b = bh / HEADS, hh = bh % HEADS;
    const unsigned short* qbase = qkv + (long)b * SEQ * 2304 + hh * 64;
    const unsigned short* kbase = qbase + 768;

#pragma unroll
    for (int u = 0; u < 5; ++u) {
        int c = tid + u * 512;
        if (c < 2304) {
            int j = c >> 3, cb = c & 7;
            int gj = j > 256 ? 256 : j;
            const unsigned short* g = kbase + (long)gj * 2304 + ((cb ^ (j & 7)) << 3);
            __builtin_amdgcn_global_load_lds(
                (const __attribute__((address_space(1))) void*)g,
                (__attribute__((address_space(3))) void*)&sh[j * 64 + cb * 8], 16, 0, 0);
        }
    }
#pragma unroll
    for (int u = 0; u < 5; ++u) {
        int c = tid + u * 512;
        if (c < 2368) {
            const unsigned short* g = vt + (long)bh * VT_Z + c * 8;
            __builtin_amdgcn_global_load_lds(
                (const __attribute__((address_space(1))) void*)g,
                (__attribute__((address_space(3))) void*)&sh[18432 + c * 8], 16, 0, 0);
        }
    }
    __syncthreads();

    const int arow = qc * 128 + w * 16 + (lane & 15);
    const int garow = arow > 256 ? 256 : arow;
    f32x4 s[18] = {};
#pragma unroll
    for (int ks = 0; ks < 2; ++ks) {
        bf16x8 aq = *(const bf16x8*)(qbase + (long)garow * 2304 + ks * 32 + (lane >> 4) * 8);
        int cb = ks * 4 + (lane >> 4);
#pragma unroll
        for (int nf = 0; nf < 18; ++nf) {
            int brow = nf * 16 + (lane & 15);
            bf16x8 bk = *(const bf16x8*)&sh[brow * 64 + ((cb ^ (brow & 7)) << 3)];
            MFMA16(s[nf], aq, bk);
        }
    }

    float inv[4];
#pragma unroll
    for (int j = 0; j < 4; ++j) {
        float m_ = -3.0e38f;
#pragma unroll
        for (int nf = 0; nf < 18; ++nf) {
            int col = nf * 16 + (lane & 15);
            float xv = (col < SEQ) ? s[nf][j] * SCALE : -3.0e38f;
            s[nf][j] = xv;
            m_ = fmaxf(m_, xv);
        }
#pragma unroll
        for (int off = 1; off < 16; off <<= 1) m_ = fmaxf(m_, __shfl_xor(m_, off));
        float sm = 0.f;
#pragma unroll
        for (int nf = 0; nf < 18; ++nf) {
            float e = __expf(s[nf][j] - m_);
            s[nf][j] = e;
            sm += e;
        }
#pragma unroll
        for (int off = 1; off < 16; off <<= 1) sm += __shfl_xor(sm, off);
        inv[j] = 1.0f / sm;
    }
#pragma unroll
    for (int nf = 0; nf < 18; ++nf) {
        int col = nf * 16 + (lane & 15);
#pragma unroll
        for (int j = 0; j < 4; ++j) {
            int row = w * 16 + (lane >> 4) * 4 + j;
            sh[37376 + row * 296 + col] = f2bf(s[nf][j] * inv[j]);
        }
    }
    __syncthreads();

    f32x4 oa[4] = {};
    const int prow = w * 16 + (lane & 15);
#pragma unroll
    for (int ks = 0; ks < 9; ++ks) {
        bf16x8 ap = *(const bf16x8*)&sh[37376 + prow * 296 + ks * 32 + (lane >> 4) * 8];
#pragma unroll
        for (int n = 0; n < 4; ++n) {
            int drow = n * 16 + (lane & 15);
            bf16x8 bv = *(const bf16x8*)&sh[18432 + drow * VT_LD + ks * 32 + (lane >> 4) * 8];
            MFMA16(oa[n], ap, bv);
        }
    }
#pragma unroll
    for (int n = 0; n < 4; ++n) {
        int col = hh * 64 + n * 16 + (lane & 15);
#pragma unroll
        for (int j = 0; j < 4; ++j) {
            int gr = qc * 128 + w * 16 + (lane >> 4) * 4 + j;
            if (gr < SEQ)
                o[((long)(b * SEQ + gr)) * DIM + col] = f2bf(oa[n][j]);
        }
    }
}

// ---------------------------------------------------------------------------
// 128x128 / BK=64 / dbuf 64KB / 2 blocks/CU bf16 MFMA GEMM (R6 proven).
// SPLIT=1: blockIdx.y = K-half; both halves atomicAdd fp32 into C (which
// already holds the residual); half 0 adds bias.  Removes the resid read.
// ---------------------------------------------------------------------------
template <int NK, int ACT, int OBF, int SPLIT>
__global__ __launch_bounds__(256, 2) void gemmd_kernel(
    const unsigned short* __restrict__ A,
    const unsigned short* __restrict__ Bt,
    const float* __restrict__ bias,
    const float* __restrict__ resid,
    void* __restrict__ C,
    int M, int GY, int lda, int ldb, int ldc) {
    __shared__ unsigned short sh[32768];
    const int tid = threadIdx.x;
    const int lane = tid & 63;
    const int w = tid >> 6;
    const int wr = w >> 1, wc = w & 1;

    const int nwg = gridDim.x;
    const int orig = blockIdx.x;
    const int q = nwg >> 3, r = nwg & 7;
    const int xcd = orig & 7, idx = orig >> 3;
    const int wg = (xcd < r ? xcd * (q + 1) : r * (q + 1) + (xcd - r) * q) + idx;
    const int bm = (wg / GY) * 128;
    const int bn = (wg % GY) * 128;
    const int half = SPLIT ? blockIdx.y : 0;

    const unsigned short* Ag = A + (long)bm * lda + (SPLIT ? half * NK * 64 : 0);
    const unsigned short* Bg = Bt + (long)bn * ldb + (SPLIT ? half * NK * 64 : 0);

    auto stage = [&](int kt) {
        unsigned short* La = &sh[(kt & 1) * 16384];
        unsigned short* Lb = La + 8192;
#pragma unroll
        for (int u = 0; u < 4; ++u) {
            int c = tid + u * 256;
            int lr = c >> 3, cb = c & 7;
            int sw = (cb ^ (lr & 7)) << 3;
            const unsigned short* ga = Ag + (long)lr * lda + kt * 64 + sw;
            __builtin_amdgcn_global_load_lds(
                (const __attribute__((address_space(1))) void*)ga,
                (__attribute__((address_space(3))) void*)&La[lr * 64 + (cb << 3)], 16, 0, 0);
            const unsigned short* gb = Bg + (long)lr * ldb + kt * 64 + sw;
            __builtin_amdgcn_global_load_lds(
                (const __attribute__((address_space(1))) void*)gb,
                (__attribute__((address_space(3))) void*)&Lb[lr * 64 + (cb << 3)], 16, 0, 0);
        }
    };
    auto ldA = [&](int p, int m, int ks) {
        int row = wr * 64 + m * 16 + (lane & 15);
        int cb = ks * 4 + (lane >> 4);
        return *(const bf16x8*)&sh[p * 16384 + row * 64 + ((cb ^ (row & 7)) << 3)];
    };
    auto ldB = [&](int p, int n, int ks) {
        int row = wc * 64 + n * 16 + (lane & 15);
        int cb = ks * 4 + (lane >> 4);
        return *(const bf16x8*)&sh[p * 16384 + 8192 + row * 64 + ((cb ^ (row & 7)) << 3)];
    };

    f32x4 acc[4][4] = {};

    stage(0); stage(1);
    asm volatile("s_waitcnt vmcnt(8)" ::: "memory");
    SBAR();

    for (int kt = 0; kt < NK; ++kt) {
        const int p = kt & 1;
        bf16x8 a[4][2], b[4][2];
#pragma unroll
        for (int m = 0; m < 4; ++m) { a[m][0] = ldA(p, m, 0); a[m][1] = ldA(p, m, 1); }
#pragma unroll
        for (int n = 0; n < 4; ++n) { b[n][0] = ldB(p, n, 0); b[n][1] = ldB(p, n, 1); }
        SBAR();
        if (kt + 2 < NK) stage(kt + 2);
        LGKM0();
        __builtin_amdgcn_s_setprio(1);
#pragma unroll
        for (int m = 0; m < 4; ++m)
#pragma unroll
            for (int n = 0; n < 4; ++n) {
                MFMA16(acc[m][n], a[m][0], b[n][0]);
                MFMA16(acc[m][n], a[m][1], b[n][1]);
            }
        __builtin_amdgcn_s_setprio(0);
        if (kt + 2 < NK) {
            asm volatile("s_waitcnt vmcnt(8)" ::: "memory");
        } else if (kt + 1 < NK) {
            asm volatile("s_waitcnt vmcnt(0)" ::: "memory");
        }
        SBAR();
    }

#pragma unroll
    for (int mi = 0; mi < 4; ++mi) {
        int gr0 = bm + wr * 64 + mi * 16 + (lane >> 4) * 4;
#pragma unroll
        for (int ni = 0; ni < 4; ++ni) {
            int gc = bn + wc * 64 + ni * 16 + (lane & 15);
            float bv = (bias && (!SPLIT || half == 0)) ? bias[gc] : 0.f;
#pragma unroll
            for (int j = 0; j < 4; ++j) {
                int gr = gr0 + j;
                if (gr >= M) continue;
                float v = acc[mi][ni][j] + bv;
                if (ACT) v = 0.5f * v * (1.0f + erff(v * 0.70710678118654752f));
                long ci = (long)gr * ldc + gc;
                if (SPLIT) {
                    atomicAdd(&((float*)C)[ci], v);
                } else if (OBF) {
                    ((unsigned short*)C)[ci] = f2bf(v);
                } else {
                    if (resid) v += resid[ci];
                    ((float*)C)[ci] = v;
                }
            }
        }
    }
}

// ---------------------------------------------------------------------------
// 128x128 / BK=32 / dbuf 32KB / 4 blocks/CU (R10 proven) — qkv + mlp1.
// ---------------------------------------------------------------------------
template <int NK, int ACT, int OBF>
__global__ __launch_bounds__(256, 4) void gemmd32_kernel(
    const unsigned short* __restrict__ A,
    const unsigned short* __restrict__ Bt,
    const float* __restrict__ bias,
    const float* __restrict__ resid,
    void* __restrict__ C,
    int M, int GY, int lda, int ldb, int ldc) {
    __shared__ unsigned short sh[16384];
    const int tid = threadIdx.x;
    const int lane = tid & 63;
    const int w = tid >> 6;
    const int wr = w >> 1, wc = w & 1;

    const int nwg = gridDim.x;
    const int orig = blockIdx.x;
    const int q = nwg >> 3, r = nwg & 7;
    const int xcd = orig & 7, idx = orig >> 3;
    const int wg = (xcd < r ? xcd * (q + 1) : r * (q + 1) + (xcd - r) * q) + idx;
    const int bm = (wg / GY) * 128;
    const int bn = (wg % GY) * 128;

    const unsigned short* Ag = A + (long)bm * lda;
    const unsigned short* Bg = Bt + (long)bn * ldb;

    auto stage = [&](int kt) {
        unsigned short* La = &sh[(kt & 1) * 8192];
        unsigned short* Lb = La + 4096;
#pragma unroll
        for (int u = 0; u < 2; ++u) {
            int c = tid + u * 256;
            int lr = c >> 2, cb = c & 3;
            int sw = (cb ^ (lr & 3)) << 3;
            const unsigned short* ga = Ag + (long)lr * lda + kt * 32 + sw;
            __builtin_amdgcn_global_load_lds(
                (const __attribute__((address_space(1))) void*)ga,
                (__attribute__((address_space(3))) void*)&La[lr * 32 + (cb << 3)], 16, 0, 0);
            const unsigned short* gb = Bg + (long)lr * ldb + kt * 32 + sw;
            __builtin_amdgcn_global_load_lds(
                (const __attribute__((address_space(1))) void*)gb,
                (__attribute__((address_space(3))) void*)&Lb[lr * 32 + (cb << 3)], 16, 0, 0);
        }
    };
    auto ldA = [&](int p, int m) {
        int row = wr * 64 + m * 16 + (lane & 15);
        int cb = lane >> 4;
        return *(const bf16x8*)&sh[p * 8192 + row * 32 + ((cb ^ (row & 3)) << 3)];
    };
    auto ldB = [&](int p, int n) {
        int row = wc * 64 + n * 16 + (lane & 15);
        int cb = lane >> 4;
        return *(const bf16x8*)&sh[p * 8192 + 4096 + row * 32 + ((cb ^ (row & 3)) << 3)];
    };

    f32x4 acc[4][4] = {};

    stage(0); stage(1);
    asm volatile("s_waitcnt vmcnt(4)" ::: "memory");
    SBAR();

    for (int kt = 0; kt < NK; ++kt) {
        const int p = kt & 1;
        bf16x8 a[4], b[4];
#pragma unroll
        for (int m = 0; m < 4; ++m) a[m] = ldA(p, m);
#pragma unroll
        for (int n = 0; n < 4; ++n) b[n] = ldB(p, n);
        SBAR();
        if (kt + 2 < NK) stage(kt + 2);
        LGKM0();
        __builtin_amdgcn_s_setprio(1);
#pragma unroll
        for (int m = 0; m < 4; ++m)
#pragma unroll
            for (int n = 0; n < 4; ++n)
                MFMA16(acc[m][n], a[m], b[n]);
        __builtin_amdgcn_s_setprio(0);
        if (kt + 2 < NK) {
            asm volatile("s_waitcnt vmcnt(4)" ::: "memory");
        } else if (kt + 1 < NK) {
            asm volatile("s_waitcnt vmcnt(0)" ::: "memory");
        }
        SBAR();
    }

#pragma unroll
    for (int mi = 0; mi < 4; ++mi) {
        int gr0 = bm + wr * 64 + mi * 16 + (lane >> 4) * 4;
#pragma unroll
        for (int ni = 0; ni < 4; ++ni) {
            int gc = bn + wc * 64 + ni * 16 + (lane & 15);
            float bv = bias ? bias[gc] : 0.f;
#pragma unroll
            for (int j = 0; j < 4; ++j) {
                int gr = gr0 + j;
                if (gr >= M) continue;
                float v = acc[mi][ni][j] + bv;
                if (ACT) v = 0.5f * v * (1.0f + erff(v * 0.70710678118654752f));
                long ci = (long)gr * ldc + gc;
                if (OBF) {
                    ((unsigned short*)C)[ci] = f2bf(v);
                } else {
                    if (resid) v += resid[ci];
                    ((float*)C)[ci] = v;
                }
            }
        }
    }
}

// ---------------------------------------------------------------------------
// fp32 GEMM for the tiny classifier head
// ---------------------------------------------------------------------------
__global__ void gemm_f32_kernel(const float* __restrict__ A,
                                const float* __restrict__ W,
                                const float* __restrict__ bias,
                                float* __restrict__ C,
                                int M, int N, int K) {
    __shared__ float As[16][65];
    __shared__ float Bs[16][65];
    int bm = blockIdx.x * 64, bn = blockIdx.y * 64;
    int t = threadIdx.x;
    int tx = t & 15, ty = t >> 4;
    float acc[4][4] = {};
    for (int k0 = 0; k0 < K; k0 += 16) {
        {
            int ar = bm + (t >> 2);
            int ac = k0 + (t & 3) * 4;
            float4 av = make_float4(0.f, 0.f, 0.f, 0.f);
            if (ar < M) av = *(const float4*)(A + (long)ar * K + ac);
            int kk = (t & 3) * 4, rr = t >> 2;
            As[kk + 0][rr] = av.x; As[kk + 1][rr] = av.y;
            As[kk + 2][rr] = av.z; As[kk + 3][rr] = av.w;
        }
        {
            int wr2 = k0 + (t >> 4);
            int wc2 = bn + (t & 15) * 4;
            float4 wv;
            wv.x = (wc2 + 0 < N) ? W[(long)wr2 * N + wc2 + 0] : 0.f;
            wv.y = (wc2 + 1 < N) ? W[(long)wr2 * N + wc2 + 1] : 0.f;
            wv.z = (wc2 + 2 < N) ? W[(long)wr2 * N + wc2 + 2] : 0.f;
            wv.w = (wc2 + 3 < N) ? W[(long)wr2 * N + wc2 + 3] : 0.f;
            int kr = t >> 4, nc = (t & 15) * 4;
            Bs[kr][nc + 0] = wv.x; Bs[kr][nc + 1] = wv.y;
            Bs[kr][nc + 2] = wv.z; Bs[kr][nc + 3] = wv.w;
        }
        __syncthreads();
#pragma unroll
        for (int kk = 0; kk < 16; ++kk) {
            float a0 = As[kk][ty * 4 + 0], a1 = As[kk][ty * 4 + 1];
            float a2 = As[kk][ty * 4 + 2], a3 = As[kk][ty * 4 + 3];
            float b0 = Bs[kk][tx], b1 = Bs[kk][tx + 16];
            float b2 = Bs[kk][tx + 32], b3 = Bs[kk][tx + 48];
            acc[0][0] += a0 * b0; acc[0][1] += a0 * b1; acc[0][2] += a0 * b2; acc[0][3] += a0 * b3;
            acc[1][0] += a1 * b0; acc[1][1] += a1 * b1; acc[1][2] += a1 * b2; acc[1][3] += a1 * b3;
            acc[2][0] += a2 * b0; acc[2][1] += a2 * b1; acc[2][2] += a2 * b2; acc[2][3] += a2 * b3;
            acc[3][0] += a3 * b0; acc[3][1] += a3 * b1; acc[3][2] += a3 * b2; acc[3][3] += a3 * b3;
        }
        __syncthreads();
    }
#pragma unroll
    for (int i = 0; i < 4; ++i) {
        int r = bm + ty * 4 + i;
        if (r >= M) continue;
#pragma unroll
        for (int j = 0; j < 4; ++j) {
            int c = bn + tx + 16 * j;
            if (c >= N) continue;
            C[(long)r * N + c] = acc[i][j] + (bias ? bias[c] : 0.f);
        }
    }
}

// ---------------------------------------------------------------------------
// Orchestration
// ---------------------------------------------------------------------------
extern "C" void kernel_launch(void* const* d_in, const int* in_sizes, int n_in,
                              void* d_out, int out_size, void* d_ws, size_t ws_size,
                              hipStream_t stream) {
    const float* x        = (const float*)d_in[0];
    const float* conv_w   = (const float*)d_in[1];
    const float* conv_b   = (const float*)d_in[2];
    const float* pos      = (const float*)d_in[3];
    const float* cls_tok  = (const float*)d_in[4];
    const float* ln1_w    = (const float*)d_in[5];
    const float* ln1_b    = (const float*)d_in[6];
    const float* qkv_w    = (const float*)d_in[7];
    const float* out_w    = (const float*)d_in[8];
    const float* out_b    = (const float*)d_in[9];
    const float* ln2_w    = (const float*)d_in[10];
    const float* ln2_b    = (const float*)d_in[11];
    const float* mlp_w1   = (const float*)d_in[12];
    const float* mlp_b1   = (const float*)d_in[13];
    const float* mlp_w2   = (const float*)d_in[14];
    const float* mlp_b2   = (const float*)d_in[15];
    const float* cls_ln_w = (const float*)d_in[16];
    const float* cls_ln_b = (const float*)d_in[17];
    const float* head_w   = (const float*)d_in[18];
    const float* head_b   = (const float*)d_in[19];
    float* out = (float*)d_out;

    char* cur = (char*)d_ws;
    auto alloc = [&](size_t bytes) {
        void* p = cur; cur += (bytes + 255) & ~(size_t)255; return p;
    };
    float*          h      = (float*)alloc((size_t)PAD_ROWS * DIM * 4);
    unsigned short* z_bf   = (unsigned short*)alloc((size_t)PAD_A * DIM * 2);
    unsigned short* qkv_bf = (unsigned short*)alloc((size_t)ROWS * 3 * DIM * 2);
    unsigned short* o_bf   = (unsigned short*)alloc((size_t)PAD_ROWS * DIM * 2);
    unsigned short* m1     = (unsigned short*)alloc((size_t)PAD_ROWS * DIM_MLP * 2);
    unsigned short* vt     = (unsigned short*)alloc((size_t)BATCH * HEADS * VT_Z * 2);
    float*          clsz   = (float*)alloc((size_t)BATCH * DIM * 4);
    size_t used = (size_t)(cur - (char*)d_ws);
    bool all_layers = (ws_size - used) >= (size_t)12 * WL_TOT * 2 + 256;
    unsigned short* wAll = (unsigned short*)alloc((all_layers ? (size_t)12 : (size_t)1) * WL_TOT * 2);

    patch_embed_kernel<<<ROWS, 256, 0, stream>>>(x, conv_w, conv_b, pos, cls_tok, h);

    if (all_layers)
        transpose_all_kernel<12><<<12 * 1728, 256, 0, stream>>>(
            qkv_w, out_w, mlp_w1, mlp_w2, wAll);

    for (int l = 0; l < DEPTH; ++l) {
        unsigned short* wL = wAll + (all_layers ? (long)l * WL_TOT : 0);
        if (!all_layers)
            transpose_all_kernel<1><<<1728, 256, 0, stream>>>(
                qkv_w + (long)l * DIM * 3 * DIM, out_w + (long)l * DIM * DIM,
                mlp_w1 + (long)l * DIM * DIM_MLP, mlp_w2 + (long)l * DIM_MLP * DIM, wL);
        unsigned short* qkvwT = wL + WL_QKV;
        unsigned short* owT   = wL + WL_OW;
        unsigned short* w1T   = wL + WL_W1;
        unsigned short* w2T   = wL + WL_W2;

        layernorm2_kernel<1><<<ROWS / 4, 256, 0, stream>>>(
            h, DIM, ln1_w + (long)l * DIM, ln1_b + (long)l * DIM, z_bf);

        // qkv = z @ qkv_w   [8224 x 2304], K=768  (BK=32, 4 blk/CU)
        gemmd32_kernel<24, 0, 1><<<65 * 18, 256, 0, stream>>>(
            z_bf, qkvwT, nullptr, nullptr, qkv_bf, ROWS, 18, DIM, DIM, 3 * DIM);

        // V^T repack then fused attention
        v_repack2_kernel<<<BATCH * HEADS, 256, 0, stream>>>(qkv_bf, vt);
        attn2_kernel<<<384 * 3, 512, 0, stream>>>(qkv_bf, vt, o_bf);

        // h = o @ out_w + out_b + h   (fp32, in-place residual), K=768 (R11 proven)
        gemmd_kernel<12, 0, 0, 0><<<65 * 6, 256, 0, stream>>>(
            o_bf, owT, out_b + (long)l * DIM, h, h, ROWS, 6, DIM, DIM, DIM);

        layernorm2_kernel<1><<<ROWS / 4, 256, 0, stream>>>(
            h, DIM, ln2_w + (long)l * DIM, ln2_b + (long)l * DIM, z_bf);

        // m1 = gelu(z @ w1 + b1)   [8224 x 3072], K=768  (BK=32, 4 blk/CU)
        gemmd32_kernel<24, 1, 1><<<65 * 24, 256, 0, stream>>>(
            z_bf, w1T, mlp_b1 + (long)l * DIM_MLP, nullptr, m1, ROWS, 24, DIM, DIM, DIM_MLP);

        // h += m1 @ w2 + b2   split-K=2, atomic fp32 epilogue (h holds resid)
        gemmd_kernel<24, 0, 0, 1><<<dim3(65 * 6, 2), 256, 0, stream>>>(
            m1, w2T, mlp_b2 + (long)l * DIM, nullptr, h, ROWS, 6, DIM_MLP, DIM_MLP, DIM);
    }

    layernorm2_kernel<0><<<BATCH / 4, 256, 0, stream>>>(
        h, (long)SEQ * DIM, cls_ln_w, cls_ln_b, clsz);
    gemm_f32_kernel<<<dim3(1, 16), 256, 0, stream>>>(
        clsz, head_w, head_b, out, BATCH, NUM_CLASSES, DIM);
}

// Round 16
// 3885.199 us; speedup vs baseline: 1.0537x; 1.0536x over previous
//
#include <hip/hip_runtime.h>
#include <math.h>

#define DIM 768
#define DEPTH 12
#define HEADS 12
#define DIM_HEAD 64
#define DIM_MLP 3072
#define PATCH 16
#define NUM_PATCHES 256
#define SEQ 257
#define NUM_CLASSES 1000
#define BATCH 32
#define SCALE 0.125f
#define EPS 1e-5f
#define ROWS 8224         // BATCH*SEQ
#define PAD_ROWS 8320     // 65*128
#define PAD_A 8448

// V^T buffer geometry: [bh][64][VT_LD], bf16
#define VT_LD 296
#define VT_Z  (64 * VT_LD)

// per-layer transposed-weight element offsets
#define WL_QKV 0
#define WL_OW  (2304 * 768)
#define WL_W1  (WL_OW + 768 * 768)
#define WL_W2  (WL_W1 + 3072 * 768)
#define WL_TOT (WL_W2 + 768 * 3072)   // 14.16 MB

typedef short bf16x8 __attribute__((ext_vector_type(8)));
typedef float f32x4 __attribute__((ext_vector_type(4)));

__device__ inline unsigned short f2bf(float f) {
    union { float f; unsigned int u; } c; c.f = f;
    unsigned int u = c.u;
    return (unsigned short)((u + 0x7fffu + ((u >> 16) & 1u)) >> 16);
}

#define MFMA16(d, a, b) d = __builtin_amdgcn_mfma_f32_16x16x32_bf16(a, b, d, 0, 0, 0)
#define SBAR() asm volatile("s_barrier" ::: "memory")
#define LGKM0() asm volatile("s_waitcnt lgkmcnt(0)" ::: "memory")

// ---------------------------------------------------------------------------
// Patch embed (fp32)
// ---------------------------------------------------------------------------
__global__ void patch_embed_kernel(const float* __restrict__ x,
                                   const float* __restrict__ conv_w,
                                   const float* __restrict__ conv_b,
                                   const float* __restrict__ pos,
                                   const float* __restrict__ cls_tok,
                                   float* __restrict__ h) {
    int row = blockIdx.x;
    int b = row / SEQ;
    int r = row % SEQ;
    int t = threadIdx.x;
    float* out = h + (long)row * DIM;
    if (r == 0) {
        for (int d = t; d < DIM; d += 256)
            out[d] = cls_tok[d] + pos[d];
        return;
    }
    int p = r - 1;
    const float* xp = x + (long)b * 4096 + p * PATCH;
    float xv[PATCH];
#pragma unroll
    for (int k = 0; k < PATCH; ++k) xv[k] = xp[k];
    for (int d = t; d < DIM; d += 256) {
        float acc = conv_b[d];
#pragma unroll
        for (int k = 0; k < PATCH; ++k)
            acc += xv[k] * conv_w[k * DIM + d];
        out[d] = acc + pos[(long)r * DIM + d];
    }
}

// ---------------------------------------------------------------------------
// LayerNorm v2: one wave per row, float4, shfl_xor.
// ---------------------------------------------------------------------------
template <int OBF>
__global__ __launch_bounds__(256) void layernorm2_kernel(
    const float* __restrict__ in, long in_stride,
    const float* __restrict__ w, const float* __restrict__ bia,
    void* __restrict__ out) {
    long row = (long)blockIdx.x * 4 + (threadIdx.x >> 6);
    int lane = threadIdx.x & 63;
    const float4* src = (const float4*)(in + row * in_stride);
    float4 v[3];
#pragma unroll
    for (int k = 0; k < 3; ++k) v[k] = src[lane + 64 * k];
    float s = 0.f, q = 0.f;
#pragma unroll
    for (int k = 0; k < 3; ++k) {
        s += v[k].x + v[k].y + v[k].z + v[k].w;
        q += v[k].x * v[k].x + v[k].y * v[k].y + v[k].z * v[k].z + v[k].w * v[k].w;
    }
#pragma unroll
    for (int off = 1; off < 64; off <<= 1) {
        s += __shfl_xor(s, off);
        q += __shfl_xor(q, off);
    }
    float mu = s * (1.0f / DIM);
    float rstd = rsqrtf(q * (1.0f / DIM) - mu * mu + EPS);
    const float4* w4 = (const float4*)w;
    const float4* b4 = (const float4*)bia;
#pragma unroll
    for (int k = 0; k < 3; ++k) {
        float4 wv = w4[lane + 64 * k], bv = b4[lane + 64 * k];
        float o0 = (v[k].x - mu) * rstd * wv.x + bv.x;
        float o1 = (v[k].y - mu) * rstd * wv.y + bv.y;
        float o2 = (v[k].z - mu) * rstd * wv.z + bv.z;
        float o3 = (v[k].w - mu) * rstd * wv.w + bv.w;
        if (OBF) {
            ushort4 pv;
            pv.x = f2bf(o0); pv.y = f2bf(o1); pv.z = f2bf(o2); pv.w = f2bf(o3);
            ((ushort4*)((unsigned short*)out + row * DIM))[lane + 64 * k] = pv;
        } else {
            float4 ov = make_float4(o0, o1, o2, o3);
            ((float4*)((float*)out + row * DIM))[lane + 64 * k] = ov;
        }
    }
}

// ---------------------------------------------------------------------------
// Weight transpose v4: 128(k)x64(n) tiles -> 256B output rows.
// Read: float4 per lane (256B/row).  Write: bf16x8 16B per lane, 256B/row.
// e-rotation (ee=(e+mm)&7) keeps write-phase LDS reads ~2-way (free).
// Tiles/layer: qkv 216, ow 72, w1 288, w2 288 = 864.
// ---------------------------------------------------------------------------
template <int LAYERS>
__global__ __launch_bounds__(256) void transpose_all_kernel(
    const float* __restrict__ qw, const float* __restrict__ ow,
    const float* __restrict__ w1, const float* __restrict__ w2,
    unsigned short* __restrict__ wOut) {
    __shared__ float tile[128][69];
    int t = blockIdx.x;
    int l = t / 864; t -= l * 864;
    const float* src; unsigned short* dst; int K, N, kt, nt;
    unsigned short* wL = wOut + (long)l * WL_TOT;
    if (t < 216)      {           src = qw + (long)l * 768 * 2304; dst = wL + WL_QKV; K = 768;  N = 2304; kt = t % 6;  nt = t / 6; }
    else if (t < 288) { t -= 216; src = ow + (long)l * 768 * 768;  dst = wL + WL_OW;  K = 768;  N = 768;  kt = t % 6;  nt = t / 6; }
    else if (t < 576) { t -= 288; src = w1 + (long)l * 768 * 3072; dst = wL + WL_W1;  K = 768;  N = 3072; kt = t % 6;  nt = t / 6; }
    else              { t -= 576; src = w2 + (long)l * 3072 * 768; dst = wL + WL_W2;  K = 3072; N = 768;  kt = t % 24; nt = t / 24; }
    int k0 = kt * 128, n0 = nt * 64;
    int tid = threadIdx.x;
    // read 128 k-rows x 64 n-cols, float4 per lane
    {
        int r0 = tid >> 4, c4 = (tid & 15) * 4;
#pragma unroll
        for (int p = 0; p < 8; ++p) {
            int r = r0 + p * 16;
            float4 v = *(const float4*)(src + (long)(k0 + r) * N + n0 + c4);
            tile[r][c4 + 0] = v.x; tile[r][c4 + 1] = v.y;
            tile[r][c4 + 2] = v.z; tile[r][c4 + 3] = v.w;
        }
    }
    __syncthreads();
    // write 64 n-rows x 128 k, bf16x8 per lane (16 chunks/row via mm=tid&15)
    {
        int mm = tid & 15, kc8 = mm * 8, nr0 = tid >> 4;
#pragma unroll
        for (int p = 0; p < 4; ++p) {
            int nr = nr0 + p * 16;
            short vv[8];
#pragma unroll
            for (int e = 0; e < 8; ++e) {
                int ee = (e + mm) & 7;
                vv[ee] = (short)f2bf(tile[kc8 + ee][nr]);
            }
            *(bf16x8*)(dst + (long)(n0 + nr) * K + k0 + kc8) = *(bf16x8*)vv;
        }
    }
}

// ---------------------------------------------------------------------------
// V repack: vt[bh][d][j] = V[b,j,h,d] (bf16), j>=257 zeroed.
// ---------------------------------------------------------------------------
__global__ __launch_bounds__(256) void v_repack2_kernel(
    const unsigned short* __restrict__ qkv, unsigned short* __restrict__ vt) {
    __shared__ unsigned short lds[257 * 69 + 3];
    int z = blockIdx.x;
    int b = z / HEADS, hh = z % HEADS;
    const unsigned short* vbase = qkv + (long)b * SEQ * 2304 + 1536 + hh * 64;
    int tid = threadIdx.x;
    for (int u = tid; u < 257 * 8; u += 256) {
        int j = u >> 3, dc = u & 7;
        bf16x8 v8 = *(const bf16x8*)(vbase + (long)j * 2304 + dc * 8);
#pragma unroll
        for (int e = 0; e < 8; ++e)
            lds[j * 69 + dc * 8 + e] = (unsigned short)v8[e];
    }
    __syncthreads();
    unsigned short* out = vt + (long)z * VT_Z;
    for (int w = tid; w < 64 * 37; w += 256) {
        int d = w / 37, jc = w % 37;
        short vv[8];
#pragma unroll
        for (int e = 0; e < 8; ++e) {
            int j = jc * 8 + e;
            vv[e] = (j < SEQ) ? (short)lds[j * 69 + d] : (short)0;
        }
        *(bf16x8*)(out + d * VT_LD + jc * 8) = *(bf16x8*)vv;
    }
}

// ---------------------------------------------------------------------------
// Fused attention v3 (R10 proven): 512 threads, 128 Q-rows/block.
// ---------------------------------------------------------------------------
__global__ __launch_bounds__(512) void attn2_kernel(const unsigned short* __restrict__ qkv,
                                                    const unsigned short* __restrict__ vt,
                                                    unsigned short* __restrict__ o) {
    __shared__ unsigned short sh[75264];
    const int tid = threadIdx.x;
    const int lane = tid & 63;
    const int w = tid >> 6;

    const int nwg = gridDim.x;
    const int orig = blockIdx.x;
    const int q = nwg >> 3, r = nwg & 7;
    const int xcd = orig & 7, idx = orig >> 3;
    const int wg = (xcd < r ? xcd * (q + 1) : r * (q + 1) + (xcd - r) * q) + idx;
    const int bh = wg / 3, qc = wg % 3;
    const int b = bh / HEADS, hh = bh % HEADS;
    const unsigned short* qbase = qkv + (long)b * SEQ * 2304 + hh * 64;
    const unsigned short* kbase = qbase + 768;

#pragma unroll
    for (int u = 0; u < 5; ++u) {
        int c = tid + u * 512;
        if (c < 2304) {
            int j = c >> 3, cb = c & 7;
            int gj = j > 256 ? 256 : j;
            const unsigned short* g = kbase + (long)gj * 2304 + ((cb ^ (j & 7)) << 3);
            __builtin_amdgcn_global_load_lds(
                (const __attribute__((address_space(1))) void*)g,
                (__attribute__((address_space(3))) void*)&sh[j * 64 + cb * 8], 16, 0, 0);
        }
    }
#pragma unroll
    for (int u = 0; u < 5; ++u) {
        int c = tid + u * 512;
        if (c < 2368) {
            const unsigned short* g = vt + (long)bh * VT_Z + c * 8;
            __builtin_amdgcn_global_load_lds(
                (const __attribute__((address_space(1))) void*)g,
                (__attribute__((address_space(3))) void*)&sh[18432 + c * 8], 16, 0, 0);
        }
    }
    __syncthreads();

    const int arow = qc * 128 + w * 16 + (lane & 15);
    const int garow = arow > 256 ? 256 : arow;
    f32x4 s[18] = {};
#pragma unroll
    for (int ks = 0; ks < 2; ++ks) {
        bf16x8 aq = *(const bf16x8*)(qbase + (long)garow * 2304 + ks * 32 + (lane >> 4) * 8);
        int cb = ks * 4 + (lane >> 4);
#pragma unroll
        for (int nf = 0; nf < 18; ++nf) {
            int brow = nf * 16 + (lane & 15);
            bf16x8 bk = *(const bf16x8*)&sh[brow * 64 + ((cb ^ (brow & 7)) << 3)];
            MFMA16(s[nf], aq, bk);
        }
    }

    float inv[4];
#pragma unroll
    for (int j = 0; j < 4; ++j) {
        float m_ = -3.0e38f;
#pragma unroll
        for (int nf = 0; nf < 18; ++nf) {
            int col = nf * 16 + (lane & 15);
            float xv = (col < SEQ) ? s[nf][j] * SCALE : -3.0e38f;
            s[nf][j] = xv;
            m_ = fmaxf(m_, xv);
        }
#pragma unroll
        for (int off = 1; off < 16; off <<= 1) m_ = fmaxf(m_, __shfl_xor(m_, off));
        float sm = 0.f;
#pragma unroll
        for (int nf = 0; nf < 18; ++nf) {
            float e = __expf(s[nf][j] - m_);
            s[nf][j] = e;
            sm += e;
        }
#pragma unroll
        for (int off = 1; off < 16; off <<= 1) sm += __shfl_xor(sm, off);
        inv[j] = 1.0f / sm;
    }
#pragma unroll
    for (int nf = 0; nf < 18; ++nf) {
        int col = nf * 16 + (lane & 15);
#pragma unroll
        for (int j = 0; j < 4; ++j) {
            int row = w * 16 + (lane >> 4) * 4 + j;
            sh[37376 + row * 296 + col] = f2bf(s[nf][j] * inv[j]);
        }
    }
    __syncthreads();

    f32x4 oa[4] = {};
    const int prow = w * 16 + (lane & 15);
#pragma unroll
    for (int ks = 0; ks < 9; ++ks) {
        bf16x8 ap = *(const bf16x8*)&sh[37376 + prow * 296 + ks * 32 + (lane >> 4) * 8];
#pragma unroll
        for (int n = 0; n < 4; ++n) {
            int drow = n * 16 + (lane & 15);
            bf16x8 bv = *(const bf16x8*)&sh[18432 + drow * VT_LD + ks * 32 + (lane >> 4) * 8];
            MFMA16(oa[n], ap, bv);
        }
    }
#pragma unroll
    for (int n = 0; n < 4; ++n) {
        int col = hh * 64 + n * 16 + (lane & 15);
#pragma unroll
        for (int j = 0; j < 4; ++j) {
            int gr = qc * 128 + w * 16 + (lane >> 4) * 4 + j;
            if (gr < SEQ)
                o[((long)(b * SEQ + gr)) * DIM + col] = f2bf(oa[n][j]);
        }
    }
}

// ---------------------------------------------------------------------------
// 128x128 / BK=64 / dbuf 64KB / 2 blocks/CU bf16 MFMA GEMM (R6 proven).
// Used where grid is small (proj, mlp2).
// ---------------------------------------------------------------------------
template <int NK, int ACT, int OBF>
__global__ __launch_bounds__(256, 2) void gemmd_kernel(
    const unsigned short* __restrict__ A,
    const unsigned short* __restrict__ Bt,
    const float* __restrict__ bias,
    const float* __restrict__ resid,
    void* __restrict__ C,
    int M, int GY, int lda, int ldb, int ldc) {
    __shared__ unsigned short sh[32768];
    const int tid = threadIdx.x;
    const int lane = tid & 63;
    const int w = tid >> 6;
    const int wr = w >> 1, wc = w & 1;

    const int nwg = gridDim.x;
    const int orig = blockIdx.x;
    const int q = nwg >> 3, r = nwg & 7;
    const int xcd = orig & 7, idx = orig >> 3;
    const int wg = (xcd < r ? xcd * (q + 1) : r * (q + 1) + (xcd - r) * q) + idx;
    const int bm = (wg / GY) * 128;
    const int bn = (wg % GY) * 128;

    const unsigned short* Ag = A + (long)bm * lda;
    const unsigned short* Bg = Bt + (long)bn * ldb;

    auto stage = [&](int kt) {
        unsigned short* La = &sh[(kt & 1) * 16384];
        unsigned short* Lb = La + 8192;
#pragma unroll
        for (int u = 0; u < 4; ++u) {
            int c = tid + u * 256;
            int lr = c >> 3, cb = c & 7;
            int sw = (cb ^ (lr & 7)) << 3;
            const unsigned short* ga = Ag + (long)lr * lda + kt * 64 + sw;
            __builtin_amdgcn_global_load_lds(
                (const __attribute__((address_space(1))) void*)ga,
                (__attribute__((address_space(3))) void*)&La[lr * 64 + (cb << 3)], 16, 0, 0);
            const unsigned short* gb = Bg + (long)lr * ldb + kt * 64 + sw;
            __builtin_amdgcn_global_load_lds(
                (const __attribute__((address_space(1))) void*)gb,
                (__attribute__((address_space(3))) void*)&Lb[lr * 64 + (cb << 3)], 16, 0, 0);
        }
    };
    auto ldA = [&](int p, int m, int ks) {
        int row = wr * 64 + m * 16 + (lane & 15);
        int cb = ks * 4 + (lane >> 4);
        return *(const bf16x8*)&sh[p * 16384 + row * 64 + ((cb ^ (row & 7)) << 3)];
    };
    auto ldB = [&](int p, int n, int ks) {
        int row = wc * 64 + n * 16 + (lane & 15);
        int cb = ks * 4 + (lane >> 4);
        return *(const bf16x8*)&sh[p * 16384 + 8192 + row * 64 + ((cb ^ (row & 7)) << 3)];
    };

    f32x4 acc[4][4] = {};

    stage(0); stage(1);
    asm volatile("s_waitcnt vmcnt(8)" ::: "memory");
    SBAR();

    for (int kt = 0; kt < NK; ++kt) {
        const int p = kt & 1;
        bf16x8 a[4][2], b[4][2];
#pragma unroll
        for (int m = 0; m < 4; ++m) { a[m][0] = ldA(p, m, 0); a[m][1] = ldA(p, m, 1); }
#pragma unroll
        for (int n = 0; n < 4; ++n) { b[n][0] = ldB(p, n, 0); b[n][1] = ldB(p, n, 1); }
        SBAR();
        if (kt + 2 < NK) stage(kt + 2);
        LGKM0();
        __builtin_amdgcn_s_setprio(1);
#pragma unroll
        for (int m = 0; m < 4; ++m)
#pragma unroll
            for (int n = 0; n < 4; ++n) {
                MFMA16(acc[m][n], a[m][0], b[n][0]);
                MFMA16(acc[m][n], a[m][1], b[n][1]);
            }
        __builtin_amdgcn_s_setprio(0);
        if (kt + 2 < NK) {
            asm volatile("s_waitcnt vmcnt(8)" ::: "memory");
        } else if (kt + 1 < NK) {
            asm volatile("s_waitcnt vmcnt(0)" ::: "memory");
        }
        SBAR();
    }

#pragma unroll
    for (int mi = 0; mi < 4; ++mi) {
        int gr0 = bm + wr * 64 + mi * 16 + (lane >> 4) * 4;
#pragma unroll
        for (int ni = 0; ni < 4; ++ni) {
            int gc = bn + wc * 64 + ni * 16 + (lane & 15);
            float bv = bias ? bias[gc] : 0.f;
#pragma unroll
            for (int j = 0; j < 4; ++j) {
                int gr = gr0 + j;
                if (gr >= M) continue;
                float v = acc[mi][ni][j] + bv;
                if (ACT) v = 0.5f * v * (1.0f + erff(v * 0.70710678118654752f));
                long ci = (long)gr * ldc + gc;
                if (OBF) {
                    ((unsigned short*)C)[ci] = f2bf(v);
                } else {
                    if (resid) v += resid[ci];
                    ((float*)C)[ci] = v;
                }
            }
        }
    }
}

// ---------------------------------------------------------------------------
// 128x128 / BK=32 / dbuf 32KB / 4 blocks/CU (R10 proven) — qkv + mlp1.
// ---------------------------------------------------------------------------
template <int NK, int ACT, int OBF>
__global__ __launch_bounds__(256, 4) void gemmd32_kernel(
    const unsigned short* __restrict__ A,
    const unsigned short* __restrict__ Bt,
    const float* __restrict__ bias,
    const float* __restrict__ resid,
    void* __restrict__ C,
    int M, int GY, int lda, int ldb, int ldc) {
    __shared__ unsigned short sh[16384];
    const int tid = threadIdx.x;
    const int lane = tid & 63;
    const int w = tid >> 6;
    const int wr = w >> 1, wc = w & 1;

    const int nwg = gridDim.x;
    const int orig = blockIdx.x;
    const int q = nwg >> 3, r = nwg & 7;
    const int xcd = orig & 7, idx = orig >> 3;
    const int wg = (xcd < r ? xcd * (q + 1) : r * (q + 1) + (xcd - r) * q) + idx;
    const int bm = (wg / GY) * 128;
    const int bn = (wg % GY) * 128;

    const unsigned short* Ag = A + (long)bm * lda;
    const unsigned short* Bg = Bt + (long)bn * ldb;

    auto stage = [&](int kt) {
        unsigned short* La = &sh[(kt & 1) * 8192];
        unsigned short* Lb = La + 4096;
#pragma unroll
        for (int u = 0; u < 2; ++u) {
            int c = tid + u * 256;
            int lr = c >> 2, cb = c & 3;
            int sw = (cb ^ (lr & 3)) << 3;
            const unsigned short* ga = Ag + (long)lr * lda + kt * 32 + sw;
            __builtin_amdgcn_global_load_lds(
                (const __attribute__((address_space(1))) void*)ga,
                (__attribute__((address_space(3))) void*)&La[lr * 32 + (cb << 3)], 16, 0, 0);
            const unsigned short* gb = Bg + (long)lr * ldb + kt * 32 + sw;
            __builtin_amdgcn_global_load_lds(
                (const __attribute__((address_space(1))) void*)gb,
                (__attribute__((address_space(3))) void*)&Lb[lr * 32 + (cb << 3)], 16, 0, 0);
        }
    };
    auto ldA = [&](int p, int m) {
        int row = wr * 64 + m * 16 + (lane & 15);
        int cb = lane >> 4;
        return *(const bf16x8*)&sh[p * 8192 + row * 32 + ((cb ^ (row & 3)) << 3)];
    };
    auto ldB = [&](int p, int n) {
        int row = wc * 64 + n * 16 + (lane & 15);
        int cb = lane >> 4;
        return *(const bf16x8*)&sh[p * 8192 + 4096 + row * 32 + ((cb ^ (row & 3)) << 3)];
    };

    f32x4 acc[4][4] = {};

    stage(0); stage(1);
    asm volatile("s_waitcnt vmcnt(4)" ::: "memory");
    SBAR();

    for (int kt = 0; kt < NK; ++kt) {
        const int p = kt & 1;
        bf16x8 a[4], b[4];
#pragma unroll
        for (int m = 0; m < 4; ++m) a[m] = ldA(p, m);
#pragma unroll
        for (int n = 0; n < 4; ++n) b[n] = ldB(p, n);
        SBAR();
        if (kt + 2 < NK) stage(kt + 2);
        LGKM0();
        __builtin_amdgcn_s_setprio(1);
#pragma unroll
        for (int m = 0; m < 4; ++m)
#pragma unroll
            for (int n = 0; n < 4; ++n)
                MFMA16(acc[m][n], a[m], b[n]);
        __builtin_amdgcn_s_setprio(0);
        if (kt + 2 < NK) {
            asm volatile("s_waitcnt vmcnt(4)" ::: "memory");
        } else if (kt + 1 < NK) {
            asm volatile("s_waitcnt vmcnt(0)" ::: "memory");
        }
        SBAR();
    }

#pragma unroll
    for (int mi = 0; mi < 4; ++mi) {
        int gr0 = bm + wr * 64 + mi * 16 + (lane >> 4) * 4;
#pragma unroll
        for (int ni = 0; ni < 4; ++ni) {
            int gc = bn + wc * 64 + ni * 16 + (lane & 15);
            float bv = bias ? bias[gc] : 0.f;
#pragma unroll
            for (int j = 0; j < 4; ++j) {
                int gr = gr0 + j;
                if (gr >= M) continue;
                float v = acc[mi][ni][j] + bv;
                if (ACT) v = 0.5f * v * (1.0f + erff(v * 0.70710678118654752f));
                long ci = (long)gr * ldc + gc;
                if (OBF) {
                    ((unsigned short*)C)[ci] = f2bf(v);
                } else {
                    if (resid) v += resid[ci];
                    ((float*)C)[ci] = v;
                }
            }
        }
    }
}

// ---------------------------------------------------------------------------
// fp32 GEMM for the tiny classifier head
// ---------------------------------------------------------------------------
__global__ void gemm_f32_kernel(const float* __restrict__ A,
                                const float* __restrict__ W,
                                const float* __restrict__ bias,
                                float* __restrict__ C,
                                int M, int N, int K) {
    __shared__ float As[16][65];
    __shared__ float Bs[16][65];
    int bm = blockIdx.x * 64, bn = blockIdx.y * 64;
    int t = threadIdx.x;
    int tx = t & 15, ty = t >> 4;
    float acc[4][4] = {};
    for (int k0 = 0; k0 < K; k0 += 16) {
        {
            int ar = bm + (t >> 2);
            int ac = k0 + (t & 3) * 4;
            float4 av = make_float4(0.f, 0.f, 0.f, 0.f);
            if (ar < M) av = *(const float4*)(A + (long)ar * K + ac);
            int kk = (t & 3) * 4, rr = t >> 2;
            As[kk + 0][rr] = av.x; As[kk + 1][rr] = av.y;
            As[kk + 2][rr] = av.z; As[kk + 3][rr] = av.w;
        }
        {
            int wr2 = k0 + (t >> 4);
            int wc2 = bn + (t & 15) * 4;
            float4 wv;
            wv.x = (wc2 + 0 < N) ? W[(long)wr2 * N + wc2 + 0] : 0.f;
            wv.y = (wc2 + 1 < N) ? W[(long)wr2 * N + wc2 + 1] : 0.f;
            wv.z = (wc2 + 2 < N) ? W[(long)wr2 * N + wc2 + 2] : 0.f;
            wv.w = (wc2 + 3 < N) ? W[(long)wr2 * N + wc2 + 3] : 0.f;
            int kr = t >> 4, nc = (t & 15) * 4;
            Bs[kr][nc + 0] = wv.x; Bs[kr][nc + 1] = wv.y;
            Bs[kr][nc + 2] = wv.z; Bs[kr][nc + 3] = wv.w;
        }
        __syncthreads();
#pragma unroll
        for (int kk = 0; kk < 16; ++kk) {
            float a0 = As[kk][ty * 4 + 0], a1 = As[kk][ty * 4 + 1];
            float a2 = As[kk][ty * 4 + 2], a3 = As[kk][ty * 4 + 3];
            float b0 = Bs[kk][tx], b1 = Bs[kk][tx + 16];
            float b2 = Bs[kk][tx + 32], b3 = Bs[kk][tx + 48];
            acc[0][0] += a0 * b0; acc[0][1] += a0 * b1; acc[0][2] += a0 * b2; acc[0][3] += a0 * b3;
            acc[1][0] += a1 * b0; acc[1][1] += a1 * b1; acc[1][2] += a1 * b2; acc[1][3] += a1 * b3;
            acc[2][0] += a2 * b0; acc[2][1] += a2 * b1; acc[2][2] += a2 * b2; acc[2][3] += a2 * b3;
            acc[3][0] += a3 * b0; acc[3][1] += a3 * b1; acc[3][2] += a3 * b2; acc[3][3] += a3 * b3;
        }
        __syncthreads();
    }
#pragma unroll
    for (int i = 0; i < 4; ++i) {
        int r = bm + ty * 4 + i;
        if (r >= M) continue;
#pragma unroll
        for (int j = 0; j < 4; ++j) {
            int c = bn + tx + 16 * j;
            if (c >= N) continue;
            C[(long)r * N + c] = acc[i][j] + (bias ? bias[c] : 0.f);
        }
    }
}

// ---------------------------------------------------------------------------
// Orchestration (R11 configuration)
// ---------------------------------------------------------------------------
extern "C" void kernel_launch(void* const* d_in, const int* in_sizes, int n_in,
                              void* d_out, int out_size, void* d_ws, size_t ws_size,
                              hipStream_t stream) {
    const float* x        = (const float*)d_in[0];
    const float* conv_w   = (const float*)d_in[1];
    const float* conv_b   = (const float*)d_in[2];
    const float* pos      = (const float*)d_in[3];
    const float* cls_tok  = (const float*)d_in[4];
    const float* ln1_w    = (const float*)d_in[5];
    const float* ln1_b    = (const float*)d_in[6];
    const float* qkv_w    = (const float*)d_in[7];
    const float* out_w    = (const float*)d_in[8];
    const float* out_b    = (const float*)d_in[9];
    const float* ln2_w    = (const float*)d_in[10];
    const float* ln2_b    = (const float*)d_in[11];
    const float* mlp_w1   = (const float*)d_in[12];
    const float* mlp_b1   = (const float*)d_in[13];
    const float* mlp_w2   = (const float*)d_in[14];
    const float* mlp_b2   = (const float*)d_in[15];
    const float* cls_ln_w = (const float*)d_in[16];
    const float* cls_ln_b = (const float*)d_in[17];
    const float* head_w   = (const float*)d_in[18];
    const float* head_b   = (const float*)d_in[19];
    float* out = (float*)d_out;

    char* cur = (char*)d_ws;
    auto alloc = [&](size_t bytes) {
        void* p = cur; cur += (bytes + 255) & ~(size_t)255; return p;
    };
    float*          h      = (float*)alloc((size_t)PAD_ROWS * DIM * 4);
    unsigned short* z_bf   = (unsigned short*)alloc((size_t)PAD_A * DIM * 2);
    unsigned short* qkv_bf = (unsigned short*)alloc((size_t)ROWS * 3 * DIM * 2);
    unsigned short* o_bf   = (unsigned short*)alloc((size_t)PAD_ROWS * DIM * 2);
    unsigned short* m1     = (unsigned short*)alloc((size_t)PAD_ROWS * DIM_MLP * 2);
    unsigned short* vt     = (unsigned short*)alloc((size_t)BATCH * HEADS * VT_Z * 2);
    float*          clsz   = (float*)alloc((size_t)BATCH * DIM * 4);
    size_t used = (size_t)(cur - (char*)d_ws);
    bool all_layers = (ws_size - used) >= (size_t)12 * WL_TOT * 2 + 256;
    unsigned short* wAll = (unsigned short*)alloc((all_layers ? (size_t)12 : (size_t)1) * WL_TOT * 2);

    patch_embed_kernel<<<ROWS, 256, 0, stream>>>(x, conv_w, conv_b, pos, cls_tok, h);

    if (all_layers)
        transpose_all_kernel<12><<<12 * 864, 256, 0, stream>>>(
            qkv_w, out_w, mlp_w1, mlp_w2, wAll);

    for (int l = 0; l < DEPTH; ++l) {
        unsigned short* wL = wAll + (all_layers ? (long)l * WL_TOT : 0);
        if (!all_layers)
            transpose_all_kernel<1><<<864, 256, 0, stream>>>(
                qkv_w + (long)l * DIM * 3 * DIM, out_w + (long)l * DIM * DIM,
                mlp_w1 + (long)l * DIM * DIM_MLP, mlp_w2 + (long)l * DIM_MLP * DIM, wL);
        unsigned short* qkvwT = wL + WL_QKV;
        unsigned short* owT   = wL + WL_OW;
        unsigned short* w1T   = wL + WL_W1;
        unsigned short* w2T   = wL + WL_W2;

        layernorm2_kernel<1><<<ROWS / 4, 256, 0, stream>>>(
            h, DIM, ln1_w + (long)l * DIM, ln1_b + (long)l * DIM, z_bf);

        // qkv = z @ qkv_w   [8224 x 2304], K=768  (BK=32, 4 blk/CU)
        gemmd32_kernel<24, 0, 1><<<65 * 18, 256, 0, stream>>>(
            z_bf, qkvwT, nullptr, nullptr, qkv_bf, ROWS, 18, DIM, DIM, 3 * DIM);

        // V^T repack then fused attention
        v_repack2_kernel<<<BATCH * HEADS, 256, 0, stream>>>(qkv_bf, vt);
        attn2_kernel<<<384 * 3, 512, 0, stream>>>(qkv_bf, vt, o_bf);

        // h = o @ out_w + out_b + h   (fp32, in-place residual), K=768
        gemmd_kernel<12, 0, 0><<<65 * 6, 256, 0, stream>>>(
            o_bf, owT, out_b + (long)l * DIM, h, h, ROWS, 6, DIM, DIM, DIM);

        layernorm2_kernel<1><<<ROWS / 4, 256, 0, stream>>>(
            h, DIM, ln2_w + (long)l * DIM, ln2_b + (long)l * DIM, z_bf);

        // m1 = gelu(z @ w1 + b1)   [8224 x 3072], K=768  (BK=32, 4 blk/CU)
        gemmd32_kernel<24, 1, 1><<<65 * 24, 256, 0, stream>>>(
            z_bf, w1T, mlp_b1 + (long)l * DIM_MLP, nullptr, m1, ROWS, 24, DIM, DIM, DIM_MLP);

        // h = m1 @ w2 + b2 + h   (fp32, in-place residual), K=3072
        gemmd_kernel<48, 0, 0><<<65 * 6, 256, 0, stream>>>(
            m1, w2T, mlp_b2 + (long)l * DIM, h, h, ROWS, 6, DIM_MLP, DIM_MLP, DIM);
    }

    layernorm2_kernel<0><<<BATCH / 4, 256, 0, stream>>>(
        h, (long)SEQ * DIM, cls_ln_w, cls_ln_b, clsz);
    gemm_f32_kernel<<<dim3(1, 16), 256, 0, stream>>>(
        clsz, head_w, head_b, out, BATCH, NUM_CLASSES, DIM);
}

// Round 17
// 3860.124 us; speedup vs baseline: 1.0605x; 1.0065x over previous
//
#include <hip/hip_runtime.h>
#include <math.h>

#define DIM 768
#define DEPTH 12
#define HEADS 12
#define DIM_HEAD 64
#define DIM_MLP 3072
#define PATCH 16
#define NUM_PATCHES 256
#define SEQ 257
#define NUM_CLASSES 1000
#define BATCH 32
#define SCALE 0.125f
#define EPS 1e-5f
#define ROWS 8224         // BATCH*SEQ
#define PAD_ROWS 8320     // 65*128
#define PAD_A 8448

// V^T buffer geometry: [bh][64][VT_LD], bf16
#define VT_LD 296
#define VT_Z  (64 * VT_LD)

// per-layer transposed-weight element offsets
#define WL_QKV 0
#define WL_OW  (2304 * 768)
#define WL_W1  (WL_OW + 768 * 768)
#define WL_W2  (WL_W1 + 3072 * 768)
#define WL_TOT (WL_W2 + 768 * 3072)   // 14.16 MB

typedef short bf16x8 __attribute__((ext_vector_type(8)));
typedef float f32x4 __attribute__((ext_vector_type(4)));

__device__ inline unsigned short f2bf(float f) {
    union { float f; unsigned int u; } c; c.f = f;
    unsigned int u = c.u;
    return (unsigned short)((u + 0x7fffu + ((u >> 16) & 1u)) >> 16);
}

#define MFMA16(d, a, b) d = __builtin_amdgcn_mfma_f32_16x16x32_bf16(a, b, d, 0, 0, 0)
#define SBAR() asm volatile("s_barrier" ::: "memory")
#define LGKM0() asm volatile("s_waitcnt lgkmcnt(0)" ::: "memory")

// ---------------------------------------------------------------------------
// Patch embed (fp32)
// ---------------------------------------------------------------------------
__global__ void patch_embed_kernel(const float* __restrict__ x,
                                   const float* __restrict__ conv_w,
                                   const float* __restrict__ conv_b,
                                   const float* __restrict__ pos,
                                   const float* __restrict__ cls_tok,
                                   float* __restrict__ h) {
    int row = blockIdx.x;
    int b = row / SEQ;
    int r = row % SEQ;
    int t = threadIdx.x;
    float* out = h + (long)row * DIM;
    if (r == 0) {
        for (int d = t; d < DIM; d += 256)
            out[d] = cls_tok[d] + pos[d];
        return;
    }
    int p = r - 1;
    const float* xp = x + (long)b * 4096 + p * PATCH;
    float xv[PATCH];
#pragma unroll
    for (int k = 0; k < PATCH; ++k) xv[k] = xp[k];
    for (int d = t; d < DIM; d += 256) {
        float acc = conv_b[d];
#pragma unroll
        for (int k = 0; k < PATCH; ++k)
            acc += xv[k] * conv_w[k * DIM + d];
        out[d] = acc + pos[(long)r * DIM + d];
    }
}

// ---------------------------------------------------------------------------
// LayerNorm v2: one wave per row, float4, shfl_xor.
// ---------------------------------------------------------------------------
template <int OBF>
__global__ __launch_bounds__(256) void layernorm2_kernel(
    const float* __restrict__ in, long in_stride,
    const float* __restrict__ w, const float* __restrict__ bia,
    void* __restrict__ out) {
    long row = (long)blockIdx.x * 4 + (threadIdx.x >> 6);
    int lane = threadIdx.x & 63;
    const float4* src = (const float4*)(in + row * in_stride);
    float4 v[3];
#pragma unroll
    for (int k = 0; k < 3; ++k) v[k] = src[lane + 64 * k];
    float s = 0.f, q = 0.f;
#pragma unroll
    for (int k = 0; k < 3; ++k) {
        s += v[k].x + v[k].y + v[k].z + v[k].w;
        q += v[k].x * v[k].x + v[k].y * v[k].y + v[k].z * v[k].z + v[k].w * v[k].w;
    }
#pragma unroll
    for (int off = 1; off < 64; off <<= 1) {
        s += __shfl_xor(s, off);
        q += __shfl_xor(q, off);
    }
    float mu = s * (1.0f / DIM);
    float rstd = rsqrtf(q * (1.0f / DIM) - mu * mu + EPS);
    const float4* w4 = (const float4*)w;
    const float4* b4 = (const float4*)bia;
#pragma unroll
    for (int k = 0; k < 3; ++k) {
        float4 wv = w4[lane + 64 * k], bv = b4[lane + 64 * k];
        float o0 = (v[k].x - mu) * rstd * wv.x + bv.x;
        float o1 = (v[k].y - mu) * rstd * wv.y + bv.y;
        float o2 = (v[k].z - mu) * rstd * wv.z + bv.z;
        float o3 = (v[k].w - mu) * rstd * wv.w + bv.w;
        if (OBF) {
            ushort4 pv;
            pv.x = f2bf(o0); pv.y = f2bf(o1); pv.z = f2bf(o2); pv.w = f2bf(o3);
            ((ushort4*)((unsigned short*)out + row * DIM))[lane + 64 * k] = pv;
        } else {
            float4 ov = make_float4(o0, o1, o2, o3);
            ((float4*)((float*)out + row * DIM))[lane + 64 * k] = ov;
        }
    }
}

// ---------------------------------------------------------------------------
// Weight transpose v4 (R16): 128(k)x64(n) tiles, float4 reads, bf16x8 writes.
// ---------------------------------------------------------------------------
template <int LAYERS>
__global__ __launch_bounds__(256) void transpose_all_kernel(
    const float* __restrict__ qw, const float* __restrict__ ow,
    const float* __restrict__ w1, const float* __restrict__ w2,
    unsigned short* __restrict__ wOut) {
    __shared__ float tile[128][69];
    int t = blockIdx.x;
    int l = t / 864; t -= l * 864;
    const float* src; unsigned short* dst; int K, N, kt, nt;
    unsigned short* wL = wOut + (long)l * WL_TOT;
    if (t < 216)      {           src = qw + (long)l * 768 * 2304; dst = wL + WL_QKV; K = 768;  N = 2304; kt = t % 6;  nt = t / 6; }
    else if (t < 288) { t -= 216; src = ow + (long)l * 768 * 768;  dst = wL + WL_OW;  K = 768;  N = 768;  kt = t % 6;  nt = t / 6; }
    else if (t < 576) { t -= 288; src = w1 + (long)l * 768 * 3072; dst = wL + WL_W1;  K = 768;  N = 3072; kt = t % 6;  nt = t / 6; }
    else              { t -= 576; src = w2 + (long)l * 3072 * 768; dst = wL + WL_W2;  K = 3072; N = 768;  kt = t % 24; nt = t / 24; }
    int k0 = kt * 128, n0 = nt * 64;
    int tid = threadIdx.x;
    {
        int r0 = tid >> 4, c4 = (tid & 15) * 4;
#pragma unroll
        for (int p = 0; p < 8; ++p) {
            int r = r0 + p * 16;
            float4 v = *(const float4*)(src + (long)(k0 + r) * N + n0 + c4);
            tile[r][c4 + 0] = v.x; tile[r][c4 + 1] = v.y;
            tile[r][c4 + 2] = v.z; tile[r][c4 + 3] = v.w;
        }
    }
    __syncthreads();
    {
        int mm = tid & 15, kc8 = mm * 8, nr0 = tid >> 4;
#pragma unroll
        for (int p = 0; p < 4; ++p) {
            int nr = nr0 + p * 16;
            short vv[8];
#pragma unroll
            for (int e = 0; e < 8; ++e) {
                int ee = (e + mm) & 7;
                vv[ee] = (short)f2bf(tile[kc8 + ee][nr]);
            }
            *(bf16x8*)(dst + (long)(n0 + nr) * K + k0 + kc8) = *(bf16x8*)vv;
        }
    }
}

// ---------------------------------------------------------------------------
// Fused attention v3 (R10 proven): 512 threads, 128 Q-rows/block.
// vt pad cols j in [257,296) are stale but P weights there are exactly 0.
// ---------------------------------------------------------------------------
__global__ __launch_bounds__(512) void attn2_kernel(const unsigned short* __restrict__ qkv,
                                                    const unsigned short* __restrict__ vt,
                                                    unsigned short* __restrict__ o) {
    __shared__ unsigned short sh[75264];
    const int tid = threadIdx.x;
    const int lane = tid & 63;
    const int w = tid >> 6;

    const int nwg = gridDim.x;
    const int orig = blockIdx.x;
    const int q = nwg >> 3, r = nwg & 7;
    const int xcd = orig & 7, idx = orig >> 3;
    const int wg = (xcd < r ? xcd * (q + 1) : r * (q + 1) + (xcd - r) * q) + idx;
    const int bh = wg / 3, qc = wg % 3;
    const int b = bh / HEADS, hh = bh % HEADS;
    const unsigned short* qbase = qkv + (long)b * SEQ * 2304 + hh * 64;
    const unsigned short* kbase = qbase + 768;

#pragma unroll
    for (int u = 0; u < 5; ++u) {
        int c = tid + u * 512;
        if (c < 2304) {
            int j = c >> 3, cb = c & 7;
            int gj = j > 256 ? 256 : j;
            const unsigned short* g = kbase + (long)gj * 2304 + ((cb ^ (j & 7)) << 3);
            __builtin_amdgcn_global_load_lds(
                (const __attribute__((address_space(1))) void*)g,
                (__attribute__((address_space(3))) void*)&sh[j * 64 + cb * 8], 16, 0, 0);
        }
    }
#pragma unroll
    for (int u = 0; u < 5; ++u) {
        int c = tid + u * 512;
        if (c < 2368) {
            const unsigned short* g = vt + (long)bh * VT_Z + c * 8;
            __builtin_amdgcn_global_load_lds(
                (const __attribute__((address_space(1))) void*)g,
                (__attribute__((address_space(3))) void*)&sh[18432 + c * 8], 16, 0, 0);
        }
    }
    __syncthreads();

    const int arow = qc * 128 + w * 16 + (lane & 15);
    const int garow = arow > 256 ? 256 : arow;
    f32x4 s[18] = {};
#pragma unroll
    for (int ks = 0; ks < 2; ++ks) {
        bf16x8 aq = *(const bf16x8*)(qbase + (long)garow * 2304 + ks * 32 + (lane >> 4) * 8);
        int cb = ks * 4 + (lane >> 4);
#pragma unroll
        for (int nf = 0; nf < 18; ++nf) {
            int brow = nf * 16 + (lane & 15);
            bf16x8 bk = *(const bf16x8*)&sh[brow * 64 + ((cb ^ (brow & 7)) << 3)];
            MFMA16(s[nf], aq, bk);
        }
    }

    float inv[4];
#pragma unroll
    for (int j = 0; j < 4; ++j) {
        float m_ = -3.0e38f;
#pragma unroll
        for (int nf = 0; nf < 18; ++nf) {
            int col = nf * 16 + (lane & 15);
            float xv = (col < SEQ) ? s[nf][j] * SCALE : -3.0e38f;
            s[nf][j] = xv;
            m_ = fmaxf(m_, xv);
        }
#pragma unroll
        for (int off = 1; off < 16; off <<= 1) m_ = fmaxf(m_, __shfl_xor(m_, off));
        float sm = 0.f;
#pragma unroll
        for (int nf = 0; nf < 18; ++nf) {
            float e = __expf(s[nf][j] - m_);
            s[nf][j] = e;
            sm += e;
        }
#pragma unroll
        for (int off = 1; off < 16; off <<= 1) sm += __shfl_xor(sm, off);
        inv[j] = 1.0f / sm;
    }
#pragma unroll
    for (int nf = 0; nf < 18; ++nf) {
        int col = nf * 16 + (lane & 15);
#pragma unroll
        for (int j = 0; j < 4; ++j) {
            int row = w * 16 + (lane >> 4) * 4 + j;
            sh[37376 + row * 296 + col] = f2bf(s[nf][j] * inv[j]);
        }
    }
    __syncthreads();

    f32x4 oa[4] = {};
    const int prow = w * 16 + (lane & 15);
#pragma unroll
    for (int ks = 0; ks < 9; ++ks) {
        bf16x8 ap = *(const bf16x8*)&sh[37376 + prow * 296 + ks * 32 + (lane >> 4) * 8];
#pragma unroll
        for (int n = 0; n < 4; ++n) {
            int drow = n * 16 + (lane & 15);
            bf16x8 bv = *(const bf16x8*)&sh[18432 + drow * VT_LD + ks * 32 + (lane >> 4) * 8];
            MFMA16(oa[n], ap, bv);
        }
    }
#pragma unroll
    for (int n = 0; n < 4; ++n) {
        int col = hh * 64 + n * 16 + (lane & 15);
#pragma unroll
        for (int j = 0; j < 4; ++j) {
            int gr = qc * 128 + w * 16 + (lane >> 4) * 4 + j;
            if (gr < SEQ)
                o[((long)(b * SEQ + gr)) * DIM + col] = f2bf(oa[n][j]);
        }
    }
}

// ---------------------------------------------------------------------------
// 128x128 / BK=64 / dbuf 64KB / 2 blocks/CU bf16 MFMA GEMM (R6 proven).
// Used where grid is small (proj, mlp2).
// ---------------------------------------------------------------------------
template <int NK, int ACT, int OBF>
__global__ __launch_bounds__(256, 2) void gemmd_kernel(
    const unsigned short* __restrict__ A,
    const unsigned short* __restrict__ Bt,
    const float* __restrict__ bias,
    const float* __restrict__ resid,
    void* __restrict__ C,
    int M, int GY, int lda, int ldb, int ldc) {
    __shared__ unsigned short sh[32768];
    const int tid = threadIdx.x;
    const int lane = tid & 63;
    const int w = tid >> 6;
    const int wr = w >> 1, wc = w & 1;

    const int nwg = gridDim.x;
    const int orig = blockIdx.x;
    const int q = nwg >> 3, r = nwg & 7;
    const int xcd = orig & 7, idx = orig >> 3;
    const int wg = (xcd < r ? xcd * (q + 1) : r * (q + 1) + (xcd - r) * q) + idx;
    const int bm = (wg / GY) * 128;
    const int bn = (wg % GY) * 128;

    const unsigned short* Ag = A + (long)bm * lda;
    const unsigned short* Bg = Bt + (long)bn * ldb;

    auto stage = [&](int kt) {
        unsigned short* La = &sh[(kt & 1) * 16384];
        unsigned short* Lb = La + 8192;
#pragma unroll
        for (int u = 0; u < 4; ++u) {
            int c = tid + u * 256;
            int lr = c >> 3, cb = c & 7;
            int sw = (cb ^ (lr & 7)) << 3;
            const unsigned short* ga = Ag + (long)lr * lda + kt * 64 + sw;
            __builtin_amdgcn_global_load_lds(
                (const __attribute__((address_space(1))) void*)ga,
                (__attribute__((address_space(3))) void*)&La[lr * 64 + (cb << 3)], 16, 0, 0);
            const unsigned short* gb = Bg + (long)lr * ldb + kt * 64 + sw;
            __builtin_amdgcn_global_load_lds(
                (const __attribute__((address_space(1))) void*)gb,
                (__attribute__((address_space(3))) void*)&Lb[lr * 64 + (cb << 3)], 16, 0, 0);
        }
    };
    auto ldA = [&](int p, int m, int ks) {
        int row = wr * 64 + m * 16 + (lane & 15);
        int cb = ks * 4 + (lane >> 4);
        return *(const bf16x8*)&sh[p * 16384 + row * 64 + ((cb ^ (row & 7)) << 3)];
    };
    auto ldB = [&](int p, int n, int ks) {
        int row = wc * 64 + n * 16 + (lane & 15);
        int cb = ks * 4 + (lane >> 4);
        return *(const bf16x8*)&sh[p * 16384 + 8192 + row * 64 + ((cb ^ (row & 7)) << 3)];
    };

    f32x4 acc[4][4] = {};

    stage(0); stage(1);
    asm volatile("s_waitcnt vmcnt(8)" ::: "memory");
    SBAR();

    for (int kt = 0; kt < NK; ++kt) {
        const int p = kt & 1;
        bf16x8 a[4][2], b[4][2];
#pragma unroll
        for (int m = 0; m < 4; ++m) { a[m][0] = ldA(p, m, 0); a[m][1] = ldA(p, m, 1); }
#pragma unroll
        for (int n = 0; n < 4; ++n) { b[n][0] = ldB(p, n, 0); b[n][1] = ldB(p, n, 1); }
        SBAR();
        if (kt + 2 < NK) stage(kt + 2);
        LGKM0();
        __builtin_amdgcn_s_setprio(1);
#pragma unroll
        for (int m = 0; m < 4; ++m)
#pragma unroll
            for (int n = 0; n < 4; ++n) {
                MFMA16(acc[m][n], a[m][0], b[n][0]);
                MFMA16(acc[m][n], a[m][1], b[n][1]);
            }
        __builtin_amdgcn_s_setprio(0);
        if (kt + 2 < NK) {
            asm volatile("s_waitcnt vmcnt(8)" ::: "memory");
        } else if (kt + 1 < NK) {
            asm volatile("s_waitcnt vmcnt(0)" ::: "memory");
        }
        SBAR();
    }

#pragma unroll
    for (int mi = 0; mi < 4; ++mi) {
        int gr0 = bm + wr * 64 + mi * 16 + (lane >> 4) * 4;
#pragma unroll
        for (int ni = 0; ni < 4; ++ni) {
            int gc = bn + wc * 64 + ni * 16 + (lane & 15);
            float bv = bias ? bias[gc] : 0.f;
#pragma unroll
            for (int j = 0; j < 4; ++j) {
                int gr = gr0 + j;
                if (gr >= M) continue;
                float v = acc[mi][ni][j] + bv;
                if (ACT) v = 0.5f * v * (1.0f + erff(v * 0.70710678118654752f));
                long ci = (long)gr * ldc + gc;
                if (OBF) {
                    ((unsigned short*)C)[ci] = f2bf(v);
                } else {
                    if (resid) v += resid[ci];
                    ((float*)C)[ci] = v;
                }
            }
        }
    }
}

// ---------------------------------------------------------------------------
// 128x128 / BK=32 / dbuf 32KB / 4 blocks/CU (R10 proven) — qkv + mlp1.
// QKV=1: output columns gc>=1536 (V) are written TRANSPOSED into vt
// (vt[bh][d][j]); Q/K columns go to C as usual.  Eliminates v_repack.
// ---------------------------------------------------------------------------
template <int NK, int ACT, int OBF, int QKV>
__global__ __launch_bounds__(256, 4) void gemmd32_kernel(
    const unsigned short* __restrict__ A,
    const unsigned short* __restrict__ Bt,
    const float* __restrict__ bias,
    unsigned short* __restrict__ vt,
    void* __restrict__ C,
    int M, int GY, int lda, int ldb, int ldc) {
    __shared__ unsigned short sh[16384];
    const int tid = threadIdx.x;
    const int lane = tid & 63;
    const int w = tid >> 6;
    const int wr = w >> 1, wc = w & 1;

    const int nwg = gridDim.x;
    const int orig = blockIdx.x;
    const int q = nwg >> 3, r = nwg & 7;
    const int xcd = orig & 7, idx = orig >> 3;
    const int wg = (xcd < r ? xcd * (q + 1) : r * (q + 1) + (xcd - r) * q) + idx;
    const int bm = (wg / GY) * 128;
    const int bn = (wg % GY) * 128;

    const unsigned short* Ag = A + (long)bm * lda;
    const unsigned short* Bg = Bt + (long)bn * ldb;

    auto stage = [&](int kt) {
        unsigned short* La = &sh[(kt & 1) * 8192];
        unsigned short* Lb = La + 4096;
#pragma unroll
        for (int u = 0; u < 2; ++u) {
            int c = tid + u * 256;
            int lr = c >> 2, cb = c & 3;
            int sw = (cb ^ (lr & 3)) << 3;
            const unsigned short* ga = Ag + (long)lr * lda + kt * 32 + sw;
            __builtin_amdgcn_global_load_lds(
                (const __attribute__((address_space(1))) void*)ga,
                (__attribute__((address_space(3))) void*)&La[lr * 32 + (cb << 3)], 16, 0, 0);
            const unsigned short* gb = Bg + (long)lr * ldb + kt * 32 + sw;
            __builtin_amdgcn_global_load_lds(
                (const __attribute__((address_space(1))) void*)gb,
                (__attribute__((address_space(3))) void*)&Lb[lr * 32 + (cb << 3)], 16, 0, 0);
        }
    };
    auto ldA = [&](int p, int m) {
        int row = wr * 64 + m * 16 + (lane & 15);
        int cb = lane >> 4;
        return *(const bf16x8*)&sh[p * 8192 + row * 32 + ((cb ^ (row & 3)) << 3)];
    };
    auto ldB = [&](int p, int n) {
        int row = wc * 64 + n * 16 + (lane & 15);
        int cb = lane >> 4;
        return *(const bf16x8*)&sh[p * 8192 + 4096 + row * 32 + ((cb ^ (row & 3)) << 3)];
    };

    f32x4 acc[4][4] = {};

    stage(0); stage(1);
    asm volatile("s_waitcnt vmcnt(4)" ::: "memory");
    SBAR();

    for (int kt = 0; kt < NK; ++kt) {
        const int p = kt & 1;
        bf16x8 a[4], b[4];
#pragma unroll
        for (int m = 0; m < 4; ++m) a[m] = ldA(p, m);
#pragma unroll
        for (int n = 0; n < 4; ++n) b[n] = ldB(p, n);
        SBAR();
        if (kt + 2 < NK) stage(kt + 2);
        LGKM0();
        __builtin_amdgcn_s_setprio(1);
#pragma unroll
        for (int m = 0; m < 4; ++m)
#pragma unroll
            for (int n = 0; n < 4; ++n)
                MFMA16(acc[m][n], a[m], b[n]);
        __builtin_amdgcn_s_setprio(0);
        if (kt + 2 < NK) {
            asm volatile("s_waitcnt vmcnt(4)" ::: "memory");
        } else if (kt + 1 < NK) {
            asm volatile("s_waitcnt vmcnt(0)" ::: "memory");
        }
        SBAR();
    }

#pragma unroll
    for (int mi = 0; mi < 4; ++mi) {
        int gr0 = bm + wr * 64 + mi * 16 + (lane >> 4) * 4;
#pragma unroll
        for (int ni = 0; ni < 4; ++ni) {
            int gc = bn + wc * 64 + ni * 16 + (lane & 15);
            float bv = bias ? bias[gc] : 0.f;
            if (QKV && gc >= 1536) {
                // V region -> transposed into vt[bh][d][j]
                int hh2 = (gc - 1536) >> 6, dd = (gc - 1536) & 63;
#pragma unroll
                for (int j = 0; j < 4; ++j) {
                    int gr = gr0 + j;
                    if (gr >= M) continue;
                    int bb = gr / SEQ, jr = gr - bb * SEQ;
                    vt[((long)(bb * HEADS + hh2)) * VT_Z + (long)dd * VT_LD + jr] =
                        f2bf(acc[mi][ni][j] + bv);
                }
                continue;
            }
#pragma unroll
            for (int j = 0; j < 4; ++j) {
                int gr = gr0 + j;
                if (gr >= M) continue;
                float v = acc[mi][ni][j] + bv;
                if (ACT) v = 0.5f * v * (1.0f + erff(v * 0.70710678118654752f));
                long ci = (long)gr * ldc + gc;
                ((unsigned short*)C)[ci] = f2bf(v);
            }
        }
    }
}

// ---------------------------------------------------------------------------
// fp32 GEMM for the tiny classifier head
// ---------------------------------------------------------------------------
__global__ void gemm_f32_kernel(const float* __restrict__ A,
                                const float* __restrict__ W,
                                const float* __restrict__ bias,
                                float* __restrict__ C,
                                int M, int N, int K) {
    __shared__ float As[16][65];
    __shared__ float Bs[16][65];
    int bm = blockIdx.x * 64, bn = blockIdx.y * 64;
    int t = threadIdx.x;
    int tx = t & 15, ty = t >> 4;
    float acc[4][4] = {};
    for (int k0 = 0; k0 < K; k0 += 16) {
        {
            int ar = bm + (t >> 2);
            int ac = k0 + (t & 3) * 4;
            float4 av = make_float4(0.f, 0.f, 0.f, 0.f);
            if (ar < M) av = *(const float4*)(A + (long)ar * K + ac);
            int kk = (t & 3) * 4, rr = t >> 2;
            As[kk + 0][rr] = av.x; As[kk + 1][rr] = av.y;
            As[kk + 2][rr] = av.z; As[kk + 3][rr] = av.w;
        }
        {
            int wr2 = k0 + (t >> 4);
            int wc2 = bn + (t & 15) * 4;
            float4 wv;
            wv.x = (wc2 + 0 < N) ? W[(long)wr2 * N + wc2 + 0] : 0.f;
            wv.y = (wc2 + 1 < N) ? W[(long)wr2 * N + wc2 + 1] : 0.f;
            wv.z = (wc2 + 2 < N) ? W[(long)wr2 * N + wc2 + 2] : 0.f;
            wv.w = (wc2 + 3 < N) ? W[(long)wr2 * N + wc2 + 3] : 0.f;
            int kr = t >> 4, nc = (t & 15) * 4;
            Bs[kr][nc + 0] = wv.x; Bs[kr][nc + 1] = wv.y;
            Bs[kr][nc + 2] = wv.z; Bs[kr][nc + 3] = wv.w;
        }
        __syncthreads();
#pragma unroll
        for (int kk = 0; kk < 16; ++kk) {
            float a0 = As[kk][ty * 4 + 0], a1 = As[kk][ty * 4 + 1];
            float a2 = As[kk][ty * 4 + 2], a3 = As[kk][ty * 4 + 3];
            float b0 = Bs[kk][tx], b1 = Bs[kk][tx + 16];
            float b2 = Bs[kk][tx + 32], b3 = Bs[kk][tx + 48];
            acc[0][0] += a0 * b0; acc[0][1] += a0 * b1; acc[0][2] += a0 * b2; acc[0][3] += a0 * b3;
            acc[1][0] += a1 * b0; acc[1][1] += a1 * b1; acc[1][2] += a1 * b2; acc[1][3] += a1 * b3;
            acc[2][0] += a2 * b0; acc[2][1] += a2 * b1; acc[2][2] += a2 * b2; acc[2][3] += a2 * b3;
            acc[3][0] += a3 * b0; acc[3][1] += a3 * b1; acc[3][2] += a3 * b2; acc[3][3] += a3 * b3;
        }
        __syncthreads();
    }
#pragma unroll
    for (int i = 0; i < 4; ++i) {
        int r = bm + ty * 4 + i;
        if (r >= M) continue;
#pragma unroll
        for (int j = 0; j < 4; ++j) {
            int c = bn + tx + 16 * j;
            if (c >= N) continue;
            C[(long)r * N + c] = acc[i][j] + (bias ? bias[c] : 0.f);
        }
    }
}

// ---------------------------------------------------------------------------
// Orchestration
// ---------------------------------------------------------------------------
extern "C" void kernel_launch(void* const* d_in, const int* in_sizes, int n_in,
                              void* d_out, int out_size, void* d_ws, size_t ws_size,
                              hipStream_t stream) {
    const float* x        = (const float*)d_in[0];
    const float* conv_w   = (const float*)d_in[1];
    const float* conv_b   = (const float*)d_in[2];
    const float* pos      = (const float*)d_in[3];
    const float* cls_tok  = (const float*)d_in[4];
    const float* ln1_w    = (const float*)d_in[5];
    const float* ln1_b    = (const float*)d_in[6];
    const float* qkv_w    = (const float*)d_in[7];
    const float* out_w    = (const float*)d_in[8];
    const float* out_b    = (const float*)d_in[9];
    const float* ln2_w    = (const float*)d_in[10];
    const float* ln2_b    = (const float*)d_in[11];
    const float* mlp_w1   = (const float*)d_in[12];
    const float* mlp_b1   = (const float*)d_in[13];
    const float* mlp_w2   = (const float*)d_in[14];
    const float* mlp_b2   = (const float*)d_in[15];
    const float* cls_ln_w = (const float*)d_in[16];
    const float* cls_ln_b = (const float*)d_in[17];
    const float* head_w   = (const float*)d_in[18];
    const float* head_b   = (const float*)d_in[19];
    float* out = (float*)d_out;

    char* cur = (char*)d_ws;
    auto alloc = [&](size_t bytes) {
        void* p = cur; cur += (bytes + 255) & ~(size_t)255; return p;
    };
    float*          h      = (float*)alloc((size_t)PAD_ROWS * DIM * 4);
    unsigned short* z_bf   = (unsigned short*)alloc((size_t)PAD_A * DIM * 2);
    unsigned short* qkv_bf = (unsigned short*)alloc((size_t)ROWS * 3 * DIM * 2);
    unsigned short* o_bf   = (unsigned short*)alloc((size_t)PAD_ROWS * DIM * 2);
    unsigned short* m1     = (unsigned short*)alloc((size_t)PAD_ROWS * DIM_MLP * 2);
    unsigned short* vt     = (unsigned short*)alloc((size_t)BATCH * HEADS * VT_Z * 2);
    float*          clsz   = (float*)alloc((size_t)BATCH * DIM * 4);
    size_t used = (size_t)(cur - (char*)d_ws);
    bool all_layers = (ws_size - used) >= (size_t)12 * WL_TOT * 2 + 256;
    unsigned short* wAll = (unsigned short*)alloc((all_layers ? (size_t)12 : (size_t)1) * WL_TOT * 2);

    patch_embed_kernel<<<ROWS, 256, 0, stream>>>(x, conv_w, conv_b, pos, cls_tok, h);

    if (all_layers)
        transpose_all_kernel<12><<<12 * 864, 256, 0, stream>>>(
            qkv_w, out_w, mlp_w1, mlp_w2, wAll);

    for (int l = 0; l < DEPTH; ++l) {
        unsigned short* wL = wAll + (all_layers ? (long)l * WL_TOT : 0);
        if (!all_layers)
            transpose_all_kernel<1><<<864, 256, 0, stream>>>(
                qkv_w + (long)l * DIM * 3 * DIM, out_w + (long)l * DIM * DIM,
                mlp_w1 + (long)l * DIM * DIM_MLP, mlp_w2 + (long)l * DIM_MLP * DIM, wL);
        unsigned short* qkvwT = wL + WL_QKV;
        unsigned short* owT   = wL + WL_OW;
        unsigned short* w1T   = wL + WL_W1;
        unsigned short* w2T   = wL + WL_W2;

        layernorm2_kernel<1><<<ROWS / 4, 256, 0, stream>>>(
            h, DIM, ln1_w + (long)l * DIM, ln1_b + (long)l * DIM, z_bf);

        // qkv = z @ qkv_w  [8224 x 2304], K=768; V columns written into vt
        gemmd32_kernel<24, 0, 1, 1><<<65 * 18, 256, 0, stream>>>(
            z_bf, qkvwT, nullptr, vt, qkv_bf, ROWS, 18, DIM, DIM, 3 * DIM);

        // fused attention (V already transposed in vt)
        attn2_kernel<<<384 * 3, 512, 0, stream>>>(qkv_bf, vt, o_bf);

        // h = o @ out_w + out_b + h   (fp32, in-place residual), K=768
        gemmd_kernel<12, 0, 0><<<65 * 6, 256, 0, stream>>>(
            o_bf, owT, out_b + (long)l * DIM, h, h, ROWS, 6, DIM, DIM, DIM);

        layernorm2_kernel<1><<<ROWS / 4, 256, 0, stream>>>(
            h, DIM, ln2_w + (long)l * DIM, ln2_b + (long)l * DIM, z_bf);

        // m1 = gelu(z @ w1 + b1)   [8224 x 3072], K=768
        gemmd32_kernel<24, 1, 1, 0><<<65 * 24, 256, 0, stream>>>(
            z_bf, w1T, mlp_b1 + (long)l * DIM_MLP, nullptr, m1, ROWS, 24, DIM, DIM, DIM_MLP);

        // h = m1 @ w2 + b2 + h   (fp32, in-place residual), K=3072
        gemmd_kernel<48, 0, 0><<<65 * 6, 256, 0, stream>>>(
            m1, w2T, mlp_b2 + (long)l * DIM, h, h, ROWS, 6, DIM_MLP, DIM_MLP, DIM);
    }

    layernorm2_kernel<0><<<BATCH / 4, 256, 0, stream>>>(
        h, (long)SEQ * DIM, cls_ln_w, cls_ln_b, clsz);
    gemm_f32_kernel<<<dim3(1, 16), 256, 0, stream>>>(
        clsz, head_w, head_b, out, BATCH, NUM_CLASSES, DIM);
}